// Round 2
// baseline (2819.584 us; speedup 1.0000x reference)
//
#include <hip/hip_runtime.h>
#include <math.h>

// GCN-VGAE encoder, N=100000 nodes, E=1600000 edges, F=H=128, O=64 (fp32 in/out).
// Strategy:
//   - Edges partitioned by destination bucket (128 nodes), then counting-sorted
//     by SOURCE CHUNK (src>>10). All aggregate blocks sweep source space in
//     lockstep -> the hot source band stays L2-resident; L2 fills are sequential
//     streams (once per XCD) instead of random 256B fetches.
//   - Aggregation: 128-dst x 128-ch fp32 accumulator tile in 64KB LDS,
//     warp-per-edge, ds_add_f32 accumulation (2-way bank aliasing = free).
//   - Feature bf16 storage is channel-pair PERMUTED: word w of a row holds
//     true channels (w, w+64). gemm1 stores permuted; agg consumes/produces
//     permuted bf16; agg2's fp32 epilogue writes true order for gemm2.
//   - Symmetric norm factored: pre-scale rows by dinv, aggregate with RAW edge
//     weights, post-scale by dinv[c]. deg computed in bucket_prep (LDS atomics).
//   - GEMMs on MFMA (16x16x32 bf16) with SPLIT precision: A=Ahi+Alo, W=Whi+Wlo,
//     C = Ahi*Whi + Alo*Whi + Ahi*Wlo  (error ~2^-18, fp32-grade).
//   - conv2/conv3 fused: agg2 = A_norm @ h once, then one GEMM with [Wmu|Wls].

#define NBLK 1024   // coarse-partition blocks; each handles ceil(E/NBLK) edges

typedef __attribute__((ext_vector_type(8))) short bf16x8;
typedef __attribute__((ext_vector_type(4))) float f32x4;

__device__ __forceinline__ unsigned short f2bf_rne(float f) {
  unsigned int u = __float_as_uint(f);
  u += 0x7FFFu + ((u >> 16) & 1u);
  return (unsigned short)(u >> 16);
}

__device__ __forceinline__ float bf2f(unsigned short h) {
  return __uint_as_float(((unsigned int)h) << 16);
}

__device__ __forceinline__ unsigned int pack2(unsigned short a, unsigned short b) {
  return (unsigned int)a | ((unsigned int)b << 16);
}

// ---------------- CSR build: two-level atomic-free partition ----------------

// Per-block LDS histogram over dst buckets (col>>7). G[bucket][blk] layout.
__global__ __launch_bounds__(256) void hist_coarse(const int* __restrict__ col,
                                                   int* __restrict__ G,
                                                   int E, int nbuck, int epb) {
  __shared__ int h[1024];
  int blk = blockIdx.x;
  for (int i = threadIdx.x; i < nbuck; i += 256) h[i] = 0;
  __syncthreads();
  int beg = blk * epb;
  int end = min(beg + epb, E);
  for (int p = beg + threadIdx.x; p < end; p += 256)
    atomicAdd(&h[col[p] >> 7], 1);
  __syncthreads();
  for (int i = threadIdx.x; i < nbuck; i += 256)
    G[(size_t)i * NBLK + blk] = h[i];
}

// Per-bucket exclusive scan over the NBLK block-counts; emits bucket totals.
__global__ __launch_bounds__(1024) void scan_bucket(int* __restrict__ G,
                                                    int* __restrict__ tot) {
  __shared__ int s[NBLK];
  int b = blockIdx.x;
  int v = G[(size_t)b * NBLK + threadIdx.x];
  s[threadIdx.x] = v;
  __syncthreads();
  for (int off = 1; off < NBLK; off <<= 1) {
    int t = (threadIdx.x >= off) ? s[threadIdx.x - off] : 0;
    __syncthreads();
    s[threadIdx.x] += t;
    __syncthreads();
  }
  G[(size_t)b * NBLK + threadIdx.x] = s[threadIdx.x] - v;   // exclusive
  if (threadIdx.x == NBLK - 1) tot[b] = s[NBLK - 1];
}

// Exclusive scan of bucket totals -> start[0..nbuck] (start[nbuck]=E).
__global__ __launch_bounds__(1024) void scan_start(const int* __restrict__ tot,
                                                   int* __restrict__ start,
                                                   int nbuck, int E) {
  __shared__ int s[1024];
  int v = (threadIdx.x < nbuck) ? tot[threadIdx.x] : 0;
  s[threadIdx.x] = v;
  __syncthreads();
  for (int off = 1; off < 1024; off <<= 1) {
    int t = (threadIdx.x >= off) ? s[threadIdx.x - off] : 0;
    __syncthreads();
    s[threadIdx.x] += t;
    __syncthreads();
  }
  if (threadIdx.x < nbuck) start[threadIdx.x] = s[threadIdx.x] - v;
  if (threadIdx.x == 0) start[nbuck] = E;
}

// Coarse scatter: LDS cursors (start[b] + G[b][blk]); packs src|dstLow into .x.
// All writes are plain stores (L2 write-back) — zero global atomics.
__global__ __launch_bounds__(256) void partition_edges(
    const int* __restrict__ row, const int* __restrict__ col,
    const float* __restrict__ w, const int* __restrict__ G,
    const int* __restrict__ start, int2* __restrict__ part,
    int E, int nbuck, int epb) {
  __shared__ int cur[1024];
  int blk = blockIdx.x;
  for (int i = threadIdx.x; i < nbuck; i += 256)
    cur[i] = start[i] + G[(size_t)i * NBLK + blk];
  __syncthreads();
  int beg = blk * epb;
  int end = min(beg + epb, E);
  for (int p = beg + threadIdx.x; p < end; p += 256) {
    int c = col[p];
    int pos = atomicAdd(&cur[c >> 7], 1);             // LDS atomic
    part[pos] = make_int2(row[p] | ((c & 127) << 17), // src < 2^17
                          __float_as_int(w[p]));
  }
}

// Per bucket: counting-sort edges by source chunk (src>>10) so every block
// sweeps source space in the same order; also accumulate deg -> dinv.
__global__ __launch_bounds__(256) void bucket_prep(const int* __restrict__ start,
                                                   const int2* __restrict__ part,
                                                   int2* __restrict__ csr,
                                                   float* __restrict__ dinv,
                                                   int N) {
  __shared__ int hist[128];
  __shared__ int sc[128];
  __shared__ int cur[128];
  __shared__ float deg[128];
  int b = blockIdx.x;
  int ebeg = start[b], eend = start[b + 1];
  if (threadIdx.x < 128) { hist[threadIdx.x] = 0; deg[threadIdx.x] = 0.f; }
  __syncthreads();
  for (int p = ebeg + threadIdx.x; p < eend; p += 256) {
    int2 e = part[p];
    atomicAdd(&hist[(e.x & 0x1FFFF) >> 10], 1);
    atomicAdd(&deg[(e.x >> 17) & 127], __int_as_float(e.y));
  }
  __syncthreads();
  if (threadIdx.x < 128) sc[threadIdx.x] = hist[threadIdx.x];
  __syncthreads();
  for (int off = 1; off < 128; off <<= 1) {
    int t = 0;
    if (threadIdx.x < 128 && threadIdx.x >= off) t = sc[threadIdx.x - off];
    __syncthreads();
    if (threadIdx.x < 128) sc[threadIdx.x] += t;
    __syncthreads();
  }
  if (threadIdx.x < 128)
    cur[threadIdx.x] = ebeg + sc[threadIdx.x] - hist[threadIdx.x];
  __syncthreads();
  for (int p = ebeg + threadIdx.x; p < eend; p += 256) {
    int2 e = part[p];
    int pos = atomicAdd(&cur[(e.x & 0x1FFFF) >> 10], 1);   // LDS atomic
    csr[pos] = e;
  }
  int node = (b << 7) + threadIdx.x;
  if (threadIdx.x < 128 && node < N)
    dinv[node] = 1.0f / sqrtf(1.0f + deg[threadIdx.x]);
}

// Transpose + bf16-split a 128x128 fp32 W: wt_hi/wt_lo[n][k] = split(W[k][n]).
__global__ void prep_wt(const float* __restrict__ Wsrc,
                        unsigned short* __restrict__ wt_hi,
                        unsigned short* __restrict__ wt_lo) {
  int i = blockIdx.x * blockDim.x + threadIdx.x;
  if (i >= 128 * 128) return;
  int n = i & 127, k = i >> 7;
  float f = Wsrc[(size_t)k * 128 + n];
  unsigned short h = f2bf_rne(f);
  unsigned short l = f2bf_rne(f - bf2f(h));
  wt_hi[(size_t)n * 128 + k] = h;
  wt_lo[(size_t)n * 128 + k] = l;
}

// Same for concatenated [Wmu | Wls] (each 128x64), plus bias concat.
__global__ void prep_wcat_t(const float* __restrict__ Wmu, const float* __restrict__ Wls,
                            const float* __restrict__ bmu, const float* __restrict__ bls,
                            unsigned short* __restrict__ wt_hi,
                            unsigned short* __restrict__ wt_lo,
                            float* __restrict__ bcat) {
  int i = blockIdx.x * blockDim.x + threadIdx.x;
  if (i >= 128 * 128) return;
  int n = i & 127, k = i >> 7;
  float f = (n < 64) ? Wmu[(size_t)k * 64 + n] : Wls[(size_t)k * 64 + (n - 64)];
  unsigned short h = f2bf_rne(f);
  unsigned short l = f2bf_rne(f - bf2f(h));
  wt_hi[(size_t)n * 128 + k] = h;
  wt_lo[(size_t)n * 128 + k] = l;
  if (i < 128) bcat[i] = (i < 64) ? bmu[i] : bls[i - 64];
}

// C[M,128] = (A[M,128] @ W[128,128]) * rowscale[row] + bias, via split-bf16 MFMA.
// WtHi/WtLo are bf16, TRANSPOSED [n][k]. Block: 256 thr = 4 waves, C-tile 128x128,
// wave computes 64x64 (4x4 tiles of 16x16). LDS XOR-swizzle: slot ^ (row&7).
// Output: fp32 split (C0 cols<split, C1 rest) and/or bf16 mirror Cbf —
// Cbf is stored channel-pair PERMUTED: slot = (c<64) ? 2c : 2(c-64)+1.
__global__ __launch_bounds__(256) void gemm_mfma(
    const float* __restrict__ A,
    const unsigned short* __restrict__ WtHi, const unsigned short* __restrict__ WtLo,
    const float* __restrict__ bias, const float* __restrict__ rowscale,
    float* __restrict__ C0, float* __restrict__ C1,
    unsigned short* __restrict__ Cbf, int split, int M) {
  __shared__ uint4 sAhi[1024];   // [row 0..127][slot 0..7] 16B slots, swizzled
  __shared__ uint4 sAlo[1024];
  __shared__ uint4 sWhi[1024];   // [col 0..127][slot 0..7]
  __shared__ uint4 sWlo[1024];

  int tid = threadIdx.x;
  int lane = tid & 63, wid = tid >> 6;
  int wave_r = (wid >> 1) * 64, wave_c = (wid & 1) * 64;
  int lrow = lane & 15, lkb = lane >> 4;   // lkb = k-chunk 0..3
  int rowBase = blockIdx.x * 128;

  f32x4 acc[4][4];
#pragma unroll
  for (int mr = 0; mr < 4; ++mr)
#pragma unroll
    for (int nc = 0; nc < 4; ++nc) acc[mr][nc] = (f32x4){0.f, 0.f, 0.f, 0.f};

  const uint4* WtHi4 = (const uint4*)WtHi;   // row = 16 uint4 (128 bf16)
  const uint4* WtLo4 = (const uint4*)WtLo;

  for (int kt = 0; kt < 128; kt += 64) {
    __syncthreads();
    // stage W tile: 128 cols x 64 k (bf16, already split) -> swizzled LDS
#pragma unroll
    for (int j = 0; j < 4; ++j) {
      int g = tid + 256 * j;            // 0..1023
      int c = g >> 3, k8 = g & 7;
      int slot = k8 ^ (c & 7);
      sWhi[c * 8 + slot] = WtHi4[c * 16 + (kt >> 3) + k8];
      sWlo[c * 8 + slot] = WtLo4[c * 16 + (kt >> 3) + k8];
    }
    // stage A tile: 128 rows x 64 k fp32 -> split hi/lo bf16 -> swizzled LDS
#pragma unroll
    for (int j = 0; j < 4; ++j) {
      int g = tid + 256 * j;            // 0..1023
      int r = g >> 3, k8 = g & 7;
      int grow = rowBase + r;
      float4 v0 = make_float4(0.f, 0.f, 0.f, 0.f);
      float4 v1 = v0;
      if (grow < M) {
        const float4* Ar = (const float4*)(A + (size_t)grow * 128 + kt);
        v0 = Ar[k8 * 2];
        v1 = Ar[k8 * 2 + 1];
      }
      float f[8] = {v0.x, v0.y, v0.z, v0.w, v1.x, v1.y, v1.z, v1.w};
      unsigned short h[8], l[8];
#pragma unroll
      for (int q = 0; q < 8; ++q) {
        h[q] = f2bf_rne(f[q]);
        l[q] = f2bf_rne(f[q] - bf2f(h[q]));
      }
      int slot = k8 ^ (r & 7);
      sAhi[r * 8 + slot] = make_uint4(pack2(h[0], h[1]), pack2(h[2], h[3]),
                                      pack2(h[4], h[5]), pack2(h[6], h[7]));
      sAlo[r * 8 + slot] = make_uint4(pack2(l[0], l[1]), pack2(l[2], l[3]),
                                      pack2(l[4], l[5]), pack2(l[6], l[7]));
    }
    __syncthreads();
    // compute: 2 MFMA k-steps (K=32 each) per LDS tile
#pragma unroll
    for (int ks = 0; ks < 2; ++ks) {
      bf16x8 ah[4], al[4], bh[4], bl[4];
#pragma unroll
      for (int mr = 0; mr < 4; ++mr) {
        int r = wave_r + mr * 16 + lrow;
        int slot = (ks * 4 + lkb) ^ (r & 7);
        ah[mr] = *(const bf16x8*)&sAhi[r * 8 + slot];
        al[mr] = *(const bf16x8*)&sAlo[r * 8 + slot];
      }
#pragma unroll
      for (int nc = 0; nc < 4; ++nc) {
        int c = wave_c + nc * 16 + lrow;
        int slot = (ks * 4 + lkb) ^ (c & 7);
        bh[nc] = *(const bf16x8*)&sWhi[c * 8 + slot];
        bl[nc] = *(const bf16x8*)&sWlo[c * 8 + slot];
      }
#pragma unroll
      for (int mr = 0; mr < 4; ++mr)
#pragma unroll
        for (int nc = 0; nc < 4; ++nc) {
          acc[mr][nc] = __builtin_amdgcn_mfma_f32_16x16x32_bf16(
              ah[mr], bh[nc], acc[mr][nc], 0, 0, 0);
          acc[mr][nc] = __builtin_amdgcn_mfma_f32_16x16x32_bf16(
              al[mr], bh[nc], acc[mr][nc], 0, 0, 0);
          acc[mr][nc] = __builtin_amdgcn_mfma_f32_16x16x32_bf16(
              ah[mr], bl[nc], acc[mr][nc], 0, 0, 0);
        }
    }
  }

  // epilogue: D[row=(lane>>4)*4+reg][col=lane&15] per 16x16 tile
#pragma unroll
  for (int mr = 0; mr < 4; ++mr) {
    int Rb = rowBase + wave_r + mr * 16 + lkb * 4;
    float sc[4];
#pragma unroll
    for (int reg = 0; reg < 4; ++reg)
      sc[reg] = (rowscale && (Rb + reg) < M) ? rowscale[Rb + reg] : 1.0f;
#pragma unroll
    for (int nc = 0; nc < 4; ++nc) {
      int c = wave_c + nc * 16 + lrow;
      float bb = bias ? bias[c] : 0.f;
      f32x4 v = acc[mr][nc];
#pragma unroll
      for (int reg = 0; reg < 4; ++reg) {
        int R = Rb + reg;
        if (R >= M) continue;
        float val = v[reg] * sc[reg] + bb;
        if (Cbf) {
          int s = (c < 64) ? (c << 1) : (((c - 64) << 1) | 1);
          Cbf[(size_t)R * 128 + s] = f2bf_rne(val);
        }
        if (C0) {
          if (c < split) C0[(size_t)R * split + c] = val;
          else           C1[(size_t)R * split + (c - split)] = val;
        }
      }
    }
  }
}

// SpMM aggregate: one block per 128-dst bucket; 64KB LDS fp32 accumulator tile.
// Edges pre-sorted by source chunk -> all blocks sweep source space together.
// hin32: permuted bf16 words (word w = true chans (w, w+64)), 64 words/node.
// out_bf: same permuted format; out_f: TRUE-order fp32 (128 floats/node).
__global__ __launch_bounds__(512) void aggregate_lds(
    const unsigned int* __restrict__ hin32, const int* __restrict__ start,
    const int2* __restrict__ csr, const float* __restrict__ dinv,
    const float* __restrict__ bias, unsigned int* __restrict__ out_bf,
    float* __restrict__ out_f, int N, int do_relu, int scale_out) {
  __shared__ float acc[128 * 128];   // 64 KB: [dstLocal][ldsCh], ldsCh == true ch
  int b = blockIdx.x;
  int base = b << 7;
  // init with self-loop rows (prescaled by dinv at the producer)
  for (int i = threadIdx.x; i < 128 * 64; i += 512) {
    int dl = i >> 6, w = i & 63;
    float lo = 0.f, hi = 0.f;
    int node = base + dl;
    if (node < N) {
      unsigned int u = hin32[(size_t)node * 64 + w];
      lo = __uint_as_float(u << 16);
      hi = __uint_as_float(u & 0xFFFF0000u);
    }
    acc[(dl << 7) + w] = lo;
    acc[(dl << 7) + 64 + w] = hi;
  }
  __syncthreads();
  int ebeg = start[b], eend = start[b + 1];
  int nE = eend - ebeg;
  int n4 = nE & ~31;                  // batch-4 per warp x 8 warps
  int lane = threadIdx.x & 63;
  int wq = threadIdx.x >> 6;
  for (int e = ebeg + (wq << 2); e < ebeg + n4; e += 32) {
    int2 E0 = csr[e],     E1 = csr[e + 1];
    int2 E2 = csr[e + 2], E3 = csr[e + 3];
    unsigned int u0 = hin32[(size_t)(E0.x & 0x1FFFF) * 64 + lane];
    unsigned int u1 = hin32[(size_t)(E1.x & 0x1FFFF) * 64 + lane];
    unsigned int u2 = hin32[(size_t)(E2.x & 0x1FFFF) * 64 + lane];
    unsigned int u3 = hin32[(size_t)(E3.x & 0x1FFFF) * 64 + lane];
    float w0 = __int_as_float(E0.y), w1 = __int_as_float(E1.y);
    float w2 = __int_as_float(E2.y), w3 = __int_as_float(E3.y);
    int a0 = (((E0.x >> 17) & 127) << 7) + lane;
    int a1 = (((E1.x >> 17) & 127) << 7) + lane;
    int a2 = (((E2.x >> 17) & 127) << 7) + lane;
    int a3 = (((E3.x >> 17) & 127) << 7) + lane;
    atomicAdd(&acc[a0],      w0 * __uint_as_float(u0 << 16));
    atomicAdd(&acc[a0 + 64], w0 * __uint_as_float(u0 & 0xFFFF0000u));
    atomicAdd(&acc[a1],      w1 * __uint_as_float(u1 << 16));
    atomicAdd(&acc[a1 + 64], w1 * __uint_as_float(u1 & 0xFFFF0000u));
    atomicAdd(&acc[a2],      w2 * __uint_as_float(u2 << 16));
    atomicAdd(&acc[a2 + 64], w2 * __uint_as_float(u2 & 0xFFFF0000u));
    atomicAdd(&acc[a3],      w3 * __uint_as_float(u3 << 16));
    atomicAdd(&acc[a3 + 64], w3 * __uint_as_float(u3 & 0xFFFF0000u));
  }
  for (int e = ebeg + n4 + wq; e < eend; e += 8) {
    int2 E0 = csr[e];
    unsigned int u0 = hin32[(size_t)(E0.x & 0x1FFFF) * 64 + lane];
    float w0 = __int_as_float(E0.y);
    int a0 = (((E0.x >> 17) & 127) << 7) + lane;
    atomicAdd(&acc[a0],      w0 * __uint_as_float(u0 << 16));
    atomicAdd(&acc[a0 + 64], w0 * __uint_as_float(u0 & 0xFFFF0000u));
  }
  __syncthreads();
  // epilogue
  for (int i = threadIdx.x; i < 128 * 64; i += 512) {
    int dl = i >> 6, w = i & 63;
    int node = base + dl;
    if (node >= N) continue;
    float dc = dinv[node];
    float lo = acc[(dl << 7) + w] * dc;
    float hi = acc[(dl << 7) + 64 + w] * dc;
    if (bias) { lo += bias[w]; hi += bias[w + 64]; }
    if (do_relu) { lo = fmaxf(lo, 0.f); hi = fmaxf(hi, 0.f); }
    if (scale_out) { lo *= dc; hi *= dc; }
    if (out_bf) out_bf[(size_t)node * 64 + w] = pack2(f2bf_rne(lo), f2bf_rne(hi));
    if (out_f) {
      out_f[(size_t)node * 128 + w] = lo;
      out_f[(size_t)node * 128 + 64 + w] = hi;
    }
  }
}

extern "C" void kernel_launch(void* const* d_in, const int* in_sizes, int n_in,
                              void* d_out, int out_size, void* d_ws, size_t ws_size,
                              hipStream_t stream) {
  const float* x   = (const float*)d_in[0];
  const int*   ei  = (const int*)d_in[1];
  const float* ea  = (const float*)d_in[2];
  const float* W1  = (const float*)d_in[3];
  const float* b1  = (const float*)d_in[4];
  const float* Wmu = (const float*)d_in[5];
  const float* bmu = (const float*)d_in[6];
  const float* Wls = (const float*)d_in[7];
  const float* bls = (const float*)d_in[8];
  const int N = in_sizes[0] / 128;
  const int E = in_sizes[2];
  const int* row = ei;
  const int* col = ei + E;

  char* p = (char*)d_ws;
  auto alloc = [&](size_t bytes) -> void* {
    void* r = (void*)p;
    p += (bytes + 255) & ~(size_t)255;
    return r;
  };
  float* dinv    = (float*)alloc((size_t)N * 4);
  int*   start   = (int*)alloc(1028 * 4);           // nbuck+1 (<=1025), real alloc
  unsigned short* w1t_hi = (unsigned short*)alloc(128 * 128 * 2);
  unsigned short* w1t_lo = (unsigned short*)alloc(128 * 128 * 2);
  unsigned short* wct_hi = (unsigned short*)alloc(128 * 128 * 2);
  unsigned short* wct_lo = (unsigned short*)alloc(128 * 128 * 2);
  float* bcat    = (float*)alloc(128 * 4);
  int2*  csr     = (int2*)alloc((size_t)E * 8);
  float* bufA    = (float*)alloc((size_t)N * 128 * 4);          // agg2 out (fp32)
  unsigned short* bufB = (unsigned short*)alloc((size_t)N * 128 * 2);  // hs1 bf16
  unsigned short* bufC = (unsigned short*)alloc((size_t)N * 128 * 2);  // out1 bf16

  const int nbuck = (N + 127) >> 7;               // 782 dst buckets of 128 nodes
  const int epb   = (E + NBLK - 1) / NBLK;        // edges per partition block

  // Aliased scratch (dead before its alias target is first written):
  //  - part (E int2 = 12.8MB) -> bufA   (bufA first written by agg2, much later)
  //  - G / tot                -> bufB   (bufB first written by gemm1, after build)
  int2* part = (int2*)bufA;
  int*  G    = (int*)bufB;                        // nbuck*NBLK ints = 3.2MB
  int*  tot  = (int*)((char*)bufB + (size_t)nbuck * NBLK * 4);

  float* out_mu = (float*)d_out;
  float* out_ls = out_mu + (size_t)N * 64;

  prep_wt<<<64, 256, 0, stream>>>(W1, w1t_hi, w1t_lo);
  prep_wcat_t<<<64, 256, 0, stream>>>(Wmu, Wls, bmu, bls, wct_hi, wct_lo, bcat);

  hist_coarse<<<NBLK, 256, 0, stream>>>(col, G, E, nbuck, epb);
  scan_bucket<<<nbuck, NBLK, 0, stream>>>(G, tot);
  scan_start<<<1, 1024, 0, stream>>>(tot, start, nbuck, E);
  partition_edges<<<NBLK, 256, 0, stream>>>(row, col, ea, G, start, part,
                                            E, nbuck, epb);
  bucket_prep<<<nbuck, 256, 0, stream>>>(start, part, csr, dinv, N);

  int gblocks = (N + 127) / 128;
  // hs1 = (x @ W1) * dinv[row]  -> permuted bf16
  gemm_mfma<<<gblocks, 256, 0, stream>>>(x, w1t_hi, w1t_lo, nullptr, dinv,
                                         nullptr, nullptr, bufB, 128, N);
  // out1 = dinv * relu(dinv[c]*(sum w*hs1[r] + hs1[c]) + b1) -> permuted bf16
  aggregate_lds<<<nbuck, 512, 0, stream>>>((const unsigned int*)bufB, start, csr,
                                           dinv, b1, (unsigned int*)bufC,
                                           nullptr, N, 1, 1);
  // agg2 = dinv[c]*(sum w*out1[r] + out1[c])  == A_norm @ h  -> fp32 (true order)
  aggregate_lds<<<nbuck, 512, 0, stream>>>((const unsigned int*)bufC, start, csr,
                                           dinv, nullptr, nullptr, bufA, N, 0, 0);
  // [mu | logstd] = agg2 @ [Wmu | Wls] + [bmu | bls]
  gemm_mfma<<<gblocks, 256, 0, stream>>>(bufA, wct_hi, wct_lo, bcat, nullptr,
                                         out_mu, out_ls, nullptr, 64, N);
}

// Round 4
// 2819.260 us; speedup vs baseline: 1.0001x; 1.0001x over previous
//
#include <hip/hip_runtime.h>
#include <math.h>

// GCN-VGAE encoder, N=100000 nodes, E=1600000 edges, F=H=128, O=64 (fp32 in/out).
// Strategy:
//   - Edges partitioned by destination bucket (128 nodes), then counting-sorted
//     by SOURCE CHUNK (src>>10). All aggregate blocks sweep source space in
//     lockstep -> the hot source band stays L2-resident; L2 fills are sequential
//     streams (once per XCD) instead of random 256B fetches.
//   - Aggregation: 128-dst x 128-ch fp32 accumulator tile in 64KB LDS,
//     warp-per-edge, NATIVE ds_add_f32 (inline asm — HIP's atomicAdd on shared
//     float lowers to a CAS loop: ~1000 cy/edge, the round-2 regression).
//     CRITICAL: inline-asm DS ops are invisible to the compiler's waitcnt
//     tracking — every __syncthreads() after a ds_add region needs an explicit
//     "s_waitcnt lgkmcnt(0)" first, else epilogue reads race the atomics
//     (round-3 failure: absmax 2e-2/488 from stale LDS reads).
//   - Feature bf16 storage is channel-pair PERMUTED: word w of a row holds
//     true channels (w, w+64). gemm1 stores permuted; agg consumes/produces
//     permuted bf16; agg2's fp32 epilogue writes true order for gemm2.
//   - Symmetric norm factored: pre-scale rows by dinv, aggregate with RAW edge
//     weights, post-scale by dinv[c]. deg computed in bucket_prep (ds_add_f32).
//   - GEMMs on MFMA (16x16x32 bf16) with SPLIT precision: A=Ahi+Alo, W=Whi+Wlo,
//     C = Ahi*Whi + Alo*Whi + Ahi*Wlo  (error ~2^-18, fp32-grade).
//   - conv2/conv3 fused: agg2 = A_norm @ h once, then one GEMM with [Wmu|Wls].

#define NBLK 1024   // coarse-partition blocks; each handles ceil(E/NBLK) edges

typedef __attribute__((ext_vector_type(8))) short bf16x8;
typedef __attribute__((ext_vector_type(4))) float f32x4;

__device__ __forceinline__ unsigned short f2bf_rne(float f) {
  unsigned int u = __float_as_uint(f);
  u += 0x7FFFu + ((u >> 16) & 1u);
  return (unsigned short)(u >> 16);
}

__device__ __forceinline__ float bf2f(unsigned short h) {
  return __uint_as_float(((unsigned int)h) << 16);
}

__device__ __forceinline__ unsigned int pack2(unsigned short a, unsigned short b) {
  return (unsigned int)a | ((unsigned int)b << 16);
}

// Native fire-and-forget LDS float atomic add. Generic pointers to LDS carry
// the 32-bit LDS offset in their low word (aperture in the high word), so the
// truncation yields the ds byte address.
__device__ __forceinline__ void lds_fadd(float* addr, float v) {
  unsigned int off = (unsigned int)(size_t)addr;
  asm volatile("ds_add_f32 %0, %1" : : "v"(off), "v"(v) : "memory");
}

// Drain ALL outstanding DS ops (incl. inline-asm ones the compiler can't see).
// MUST precede any __syncthreads() that follows lds_fadd use.
__device__ __forceinline__ void ds_drain() {
  asm volatile("s_waitcnt lgkmcnt(0)" ::: "memory");
}

// ---------------- CSR build: two-level atomic-free partition ----------------

// Per-block LDS histogram over dst buckets (col>>7). G[bucket][blk] layout.
__global__ __launch_bounds__(256) void hist_coarse(const int* __restrict__ col,
                                                   int* __restrict__ G,
                                                   int E, int nbuck, int epb) {
  __shared__ int h[1024];
  int blk = blockIdx.x;
  for (int i = threadIdx.x; i < nbuck; i += 256) h[i] = 0;
  __syncthreads();
  int beg = blk * epb;
  int end = min(beg + epb, E);
  for (int p = beg + threadIdx.x; p < end; p += 256)
    atomicAdd(&h[col[p] >> 7], 1);
  __syncthreads();
  for (int i = threadIdx.x; i < nbuck; i += 256)
    G[(size_t)i * NBLK + blk] = h[i];
}

// Per-bucket exclusive scan over the NBLK block-counts; emits bucket totals.
__global__ __launch_bounds__(1024) void scan_bucket(int* __restrict__ G,
                                                    int* __restrict__ tot) {
  __shared__ int s[NBLK];
  int b = blockIdx.x;
  int v = G[(size_t)b * NBLK + threadIdx.x];
  s[threadIdx.x] = v;
  __syncthreads();
  for (int off = 1; off < NBLK; off <<= 1) {
    int t = (threadIdx.x >= off) ? s[threadIdx.x - off] : 0;
    __syncthreads();
    s[threadIdx.x] += t;
    __syncthreads();
  }
  G[(size_t)b * NBLK + threadIdx.x] = s[threadIdx.x] - v;   // exclusive
  if (threadIdx.x == NBLK - 1) tot[b] = s[NBLK - 1];
}

// Exclusive scan of bucket totals -> start[0..nbuck] (start[nbuck]=E).
__global__ __launch_bounds__(1024) void scan_start(const int* __restrict__ tot,
                                                   int* __restrict__ start,
                                                   int nbuck, int E) {
  __shared__ int s[1024];
  int v = (threadIdx.x < nbuck) ? tot[threadIdx.x] : 0;
  s[threadIdx.x] = v;
  __syncthreads();
  for (int off = 1; off < 1024; off <<= 1) {
    int t = (threadIdx.x >= off) ? s[threadIdx.x - off] : 0;
    __syncthreads();
    s[threadIdx.x] += t;
    __syncthreads();
  }
  if (threadIdx.x < nbuck) start[threadIdx.x] = s[threadIdx.x] - v;
  if (threadIdx.x == 0) start[nbuck] = E;
}

// Coarse scatter: LDS cursors (start[b] + G[b][blk]); packs src|dstLow into .x.
// All writes are plain stores (L2 write-back) — zero global atomics.
__global__ __launch_bounds__(256) void partition_edges(
    const int* __restrict__ row, const int* __restrict__ col,
    const float* __restrict__ w, const int* __restrict__ G,
    const int* __restrict__ start, int2* __restrict__ part,
    int E, int nbuck, int epb) {
  __shared__ int cur[1024];
  int blk = blockIdx.x;
  for (int i = threadIdx.x; i < nbuck; i += 256)
    cur[i] = start[i] + G[(size_t)i * NBLK + blk];
  __syncthreads();
  int beg = blk * epb;
  int end = min(beg + epb, E);
  for (int p = beg + threadIdx.x; p < end; p += 256) {
    int c = col[p];
    int pos = atomicAdd(&cur[c >> 7], 1);             // LDS atomic (int, native)
    part[pos] = make_int2(row[p] | ((c & 127) << 17), // src < 2^17
                          __float_as_int(w[p]));
  }
}

// Per bucket: counting-sort edges by source chunk (src>>10) so every block
// sweeps source space in the same order; also accumulate deg -> dinv.
__global__ __launch_bounds__(256) void bucket_prep(const int* __restrict__ start,
                                                   const int2* __restrict__ part,
                                                   int2* __restrict__ csr,
                                                   float* __restrict__ dinv,
                                                   int N) {
  __shared__ int hist[128];
  __shared__ int sc[128];
  __shared__ int cur[128];
  __shared__ float deg[128];
  int b = blockIdx.x;
  int ebeg = start[b], eend = start[b + 1];
  if (threadIdx.x < 128) { hist[threadIdx.x] = 0; deg[threadIdx.x] = 0.f; }
  __syncthreads();
  for (int p = ebeg + threadIdx.x; p < eend; p += 256) {
    int2 e = part[p];
    atomicAdd(&hist[(e.x & 0x1FFFF) >> 10], 1);
    lds_fadd(&deg[(e.x >> 17) & 127], __int_as_float(e.y));
  }
  ds_drain();          // asm ds_add_f32 invisible to compiler waitcnt tracking
  __syncthreads();
  if (threadIdx.x < 128) sc[threadIdx.x] = hist[threadIdx.x];
  __syncthreads();
  for (int off = 1; off < 128; off <<= 1) {
    int t = 0;
    if (threadIdx.x < 128 && threadIdx.x >= off) t = sc[threadIdx.x - off];
    __syncthreads();
    if (threadIdx.x < 128) sc[threadIdx.x] += t;
    __syncthreads();
  }
  if (threadIdx.x < 128)
    cur[threadIdx.x] = ebeg + sc[threadIdx.x] - hist[threadIdx.x];
  __syncthreads();
  for (int p = ebeg + threadIdx.x; p < eend; p += 256) {
    int2 e = part[p];
    int pos = atomicAdd(&cur[(e.x & 0x1FFFF) >> 10], 1);   // LDS atomic (int)
    csr[pos] = e;
  }
  int node = (b << 7) + threadIdx.x;
  if (threadIdx.x < 128 && node < N)
    dinv[node] = 1.0f / sqrtf(1.0f + deg[threadIdx.x]);
}

// Transpose + bf16-split a 128x128 fp32 W: wt_hi/wt_lo[n][k] = split(W[k][n]).
__global__ void prep_wt(const float* __restrict__ Wsrc,
                        unsigned short* __restrict__ wt_hi,
                        unsigned short* __restrict__ wt_lo) {
  int i = blockIdx.x * blockDim.x + threadIdx.x;
  if (i >= 128 * 128) return;
  int n = i & 127, k = i >> 7;
  float f = Wsrc[(size_t)k * 128 + n];
  unsigned short h = f2bf_rne(f);
  unsigned short l = f2bf_rne(f - bf2f(h));
  wt_hi[(size_t)n * 128 + k] = h;
  wt_lo[(size_t)n * 128 + k] = l;
}

// Same for concatenated [Wmu | Wls] (each 128x64), plus bias concat.
__global__ void prep_wcat_t(const float* __restrict__ Wmu, const float* __restrict__ Wls,
                            const float* __restrict__ bmu, const float* __restrict__ bls,
                            unsigned short* __restrict__ wt_hi,
                            unsigned short* __restrict__ wt_lo,
                            float* __restrict__ bcat) {
  int i = blockIdx.x * blockDim.x + threadIdx.x;
  if (i >= 128 * 128) return;
  int n = i & 127, k = i >> 7;
  float f = (n < 64) ? Wmu[(size_t)k * 64 + n] : Wls[(size_t)k * 64 + (n - 64)];
  unsigned short h = f2bf_rne(f);
  unsigned short l = f2bf_rne(f - bf2f(h));
  wt_hi[(size_t)n * 128 + k] = h;
  wt_lo[(size_t)n * 128 + k] = l;
  if (i < 128) bcat[i] = (i < 64) ? bmu[i] : bls[i - 64];
}

// C[M,128] = (A[M,128] @ W[128,128]) * rowscale[row] + bias, via split-bf16 MFMA.
// WtHi/WtLo are bf16, TRANSPOSED [n][k]. Block: 256 thr = 4 waves, C-tile 128x128,
// wave computes 64x64 (4x4 tiles of 16x16). LDS XOR-swizzle: slot ^ (row&7).
// Output: fp32 split (C0 cols<split, C1 rest) and/or bf16 mirror Cbf —
// Cbf is stored channel-pair PERMUTED: slot = (c<64) ? 2c : 2(c-64)+1.
__global__ __launch_bounds__(256) void gemm_mfma(
    const float* __restrict__ A,
    const unsigned short* __restrict__ WtHi, const unsigned short* __restrict__ WtLo,
    const float* __restrict__ bias, const float* __restrict__ rowscale,
    float* __restrict__ C0, float* __restrict__ C1,
    unsigned short* __restrict__ Cbf, int split, int M) {
  __shared__ uint4 sAhi[1024];   // [row 0..127][slot 0..7] 16B slots, swizzled
  __shared__ uint4 sAlo[1024];
  __shared__ uint4 sWhi[1024];   // [col 0..127][slot 0..7]
  __shared__ uint4 sWlo[1024];

  int tid = threadIdx.x;
  int lane = tid & 63, wid = tid >> 6;
  int wave_r = (wid >> 1) * 64, wave_c = (wid & 1) * 64;
  int lrow = lane & 15, lkb = lane >> 4;   // lkb = k-chunk 0..3
  int rowBase = blockIdx.x * 128;

  f32x4 acc[4][4];
#pragma unroll
  for (int mr = 0; mr < 4; ++mr)
#pragma unroll
    for (int nc = 0; nc < 4; ++nc) acc[mr][nc] = (f32x4){0.f, 0.f, 0.f, 0.f};

  const uint4* WtHi4 = (const uint4*)WtHi;   // row = 16 uint4 (128 bf16)
  const uint4* WtLo4 = (const uint4*)WtLo;

  for (int kt = 0; kt < 128; kt += 64) {
    __syncthreads();
    // stage W tile: 128 cols x 64 k (bf16, already split) -> swizzled LDS
#pragma unroll
    for (int j = 0; j < 4; ++j) {
      int g = tid + 256 * j;            // 0..1023
      int c = g >> 3, k8 = g & 7;
      int slot = k8 ^ (c & 7);
      sWhi[c * 8 + slot] = WtHi4[c * 16 + (kt >> 3) + k8];
      sWlo[c * 8 + slot] = WtLo4[c * 16 + (kt >> 3) + k8];
    }
    // stage A tile: 128 rows x 64 k fp32 -> split hi/lo bf16 -> swizzled LDS
#pragma unroll
    for (int j = 0; j < 4; ++j) {
      int g = tid + 256 * j;            // 0..1023
      int r = g >> 3, k8 = g & 7;
      int grow = rowBase + r;
      float4 v0 = make_float4(0.f, 0.f, 0.f, 0.f);
      float4 v1 = v0;
      if (grow < M) {
        const float4* Ar = (const float4*)(A + (size_t)grow * 128 + kt);
        v0 = Ar[k8 * 2];
        v1 = Ar[k8 * 2 + 1];
      }
      float f[8] = {v0.x, v0.y, v0.z, v0.w, v1.x, v1.y, v1.z, v1.w};
      unsigned short h[8], l[8];
#pragma unroll
      for (int q = 0; q < 8; ++q) {
        h[q] = f2bf_rne(f[q]);
        l[q] = f2bf_rne(f[q] - bf2f(h[q]));
      }
      int slot = k8 ^ (r & 7);
      sAhi[r * 8 + slot] = make_uint4(pack2(h[0], h[1]), pack2(h[2], h[3]),
                                      pack2(h[4], h[5]), pack2(h[6], h[7]));
      sAlo[r * 8 + slot] = make_uint4(pack2(l[0], l[1]), pack2(l[2], l[3]),
                                      pack2(l[4], l[5]), pack2(l[6], l[7]));
    }
    __syncthreads();
    // compute: 2 MFMA k-steps (K=32 each) per LDS tile
#pragma unroll
    for (int ks = 0; ks < 2; ++ks) {
      bf16x8 ah[4], al[4], bh[4], bl[4];
#pragma unroll
      for (int mr = 0; mr < 4; ++mr) {
        int r = wave_r + mr * 16 + lrow;
        int slot = (ks * 4 + lkb) ^ (r & 7);
        ah[mr] = *(const bf16x8*)&sAhi[r * 8 + slot];
        al[mr] = *(const bf16x8*)&sAlo[r * 8 + slot];
      }
#pragma unroll
      for (int nc = 0; nc < 4; ++nc) {
        int c = wave_c + nc * 16 + lrow;
        int slot = (ks * 4 + lkb) ^ (c & 7);
        bh[nc] = *(const bf16x8*)&sWhi[c * 8 + slot];
        bl[nc] = *(const bf16x8*)&sWlo[c * 8 + slot];
      }
#pragma unroll
      for (int mr = 0; mr < 4; ++mr)
#pragma unroll
        for (int nc = 0; nc < 4; ++nc) {
          acc[mr][nc] = __builtin_amdgcn_mfma_f32_16x16x32_bf16(
              ah[mr], bh[nc], acc[mr][nc], 0, 0, 0);
          acc[mr][nc] = __builtin_amdgcn_mfma_f32_16x16x32_bf16(
              al[mr], bh[nc], acc[mr][nc], 0, 0, 0);
          acc[mr][nc] = __builtin_amdgcn_mfma_f32_16x16x32_bf16(
              ah[mr], bl[nc], acc[mr][nc], 0, 0, 0);
        }
    }
  }

  // epilogue: D[row=(lane>>4)*4+reg][col=lane&15] per 16x16 tile
#pragma unroll
  for (int mr = 0; mr < 4; ++mr) {
    int Rb = rowBase + wave_r + mr * 16 + lkb * 4;
    float sc[4];
#pragma unroll
    for (int reg = 0; reg < 4; ++reg)
      sc[reg] = (rowscale && (Rb + reg) < M) ? rowscale[Rb + reg] : 1.0f;
#pragma unroll
    for (int nc = 0; nc < 4; ++nc) {
      int c = wave_c + nc * 16 + lrow;
      float bb = bias ? bias[c] : 0.f;
      f32x4 v = acc[mr][nc];
#pragma unroll
      for (int reg = 0; reg < 4; ++reg) {
        int R = Rb + reg;
        if (R >= M) continue;
        float val = v[reg] * sc[reg] + bb;
        if (Cbf) {
          int s = (c < 64) ? (c << 1) : (((c - 64) << 1) | 1);
          Cbf[(size_t)R * 128 + s] = f2bf_rne(val);
        }
        if (C0) {
          if (c < split) C0[(size_t)R * split + c] = val;
          else           C1[(size_t)R * split + (c - split)] = val;
        }
      }
    }
  }
}

// SpMM aggregate: one block per 128-dst bucket; 64KB LDS fp32 accumulator tile.
// Edges pre-sorted by source chunk -> all blocks sweep source space together.
// hin32: permuted bf16 words (word w = true chans (w, w+64)), 64 words/node.
// out_bf: same permuted format; out_f: TRUE-order fp32 (128 floats/node).
__global__ __launch_bounds__(512) void aggregate_lds(
    const unsigned int* __restrict__ hin32, const int* __restrict__ start,
    const int2* __restrict__ csr, const float* __restrict__ dinv,
    const float* __restrict__ bias, unsigned int* __restrict__ out_bf,
    float* __restrict__ out_f, int N, int do_relu, int scale_out) {
  __shared__ float acc[128 * 128];   // 64 KB: [dstLocal][ldsCh], ldsCh == true ch
  int b = blockIdx.x;
  int base = b << 7;
  // init with self-loop rows (prescaled by dinv at the producer)
  for (int i = threadIdx.x; i < 128 * 64; i += 512) {
    int dl = i >> 6, w = i & 63;
    float lo = 0.f, hi = 0.f;
    int node = base + dl;
    if (node < N) {
      unsigned int u = hin32[(size_t)node * 64 + w];
      lo = __uint_as_float(u << 16);
      hi = __uint_as_float(u & 0xFFFF0000u);
    }
    acc[(dl << 7) + w] = lo;
    acc[(dl << 7) + 64 + w] = hi;
  }
  __syncthreads();
  int ebeg = start[b], eend = start[b + 1];
  int nE = eend - ebeg;
  int n8 = nE & ~63;                  // batch-8 per warp x 8 warps
  int lane = threadIdx.x & 63;
  int wq = threadIdx.x >> 6;
  for (int e = ebeg + (wq << 3); e < ebeg + n8; e += 64) {
    int2 Ee[8];
    unsigned int uu[8];
#pragma unroll
    for (int q = 0; q < 8; ++q) Ee[q] = csr[e + q];
#pragma unroll
    for (int q = 0; q < 8; ++q)
      uu[q] = hin32[(size_t)(Ee[q].x & 0x1FFFF) * 64 + lane];
#pragma unroll
    for (int q = 0; q < 8; ++q) {
      float w = __int_as_float(Ee[q].y);
      int a = (((Ee[q].x >> 17) & 127) << 7) + lane;
      lds_fadd(&acc[a],      w * __uint_as_float(uu[q] << 16));
      lds_fadd(&acc[a + 64], w * __uint_as_float(uu[q] & 0xFFFF0000u));
    }
  }
  for (int e = ebeg + n8 + wq; e < eend; e += 8) {
    int2 E0 = csr[e];
    unsigned int u0 = hin32[(size_t)(E0.x & 0x1FFFF) * 64 + lane];
    float w0 = __int_as_float(E0.y);
    int a0 = (((E0.x >> 17) & 127) << 7) + lane;
    lds_fadd(&acc[a0],      w0 * __uint_as_float(u0 << 16));
    lds_fadd(&acc[a0 + 64], w0 * __uint_as_float(u0 & 0xFFFF0000u));
  }
  ds_drain();          // asm ds_add_f32 invisible to compiler waitcnt tracking
  __syncthreads();
  // epilogue
  for (int i = threadIdx.x; i < 128 * 64; i += 512) {
    int dl = i >> 6, w = i & 63;
    int node = base + dl;
    if (node >= N) continue;
    float dc = dinv[node];
    float lo = acc[(dl << 7) + w] * dc;
    float hi = acc[(dl << 7) + 64 + w] * dc;
    if (bias) { lo += bias[w]; hi += bias[w + 64]; }
    if (do_relu) { lo = fmaxf(lo, 0.f); hi = fmaxf(hi, 0.f); }
    if (scale_out) { lo *= dc; hi *= dc; }
    if (out_bf) out_bf[(size_t)node * 64 + w] = pack2(f2bf_rne(lo), f2bf_rne(hi));
    if (out_f) {
      out_f[(size_t)node * 128 + w] = lo;
      out_f[(size_t)node * 128 + 64 + w] = hi;
    }
  }
}

extern "C" void kernel_launch(void* const* d_in, const int* in_sizes, int n_in,
                              void* d_out, int out_size, void* d_ws, size_t ws_size,
                              hipStream_t stream) {
  const float* x   = (const float*)d_in[0];
  const int*   ei  = (const int*)d_in[1];
  const float* ea  = (const float*)d_in[2];
  const float* W1  = (const float*)d_in[3];
  const float* b1  = (const float*)d_in[4];
  const float* Wmu = (const float*)d_in[5];
  const float* bmu = (const float*)d_in[6];
  const float* Wls = (const float*)d_in[7];
  const float* bls = (const float*)d_in[8];
  const int N = in_sizes[0] / 128;
  const int E = in_sizes[2];
  const int* row = ei;
  const int* col = ei + E;

  char* p = (char*)d_ws;
  auto alloc = [&](size_t bytes) -> void* {
    void* r = (void*)p;
    p += (bytes + 255) & ~(size_t)255;
    return r;
  };
  float* dinv    = (float*)alloc((size_t)N * 4);
  int*   start   = (int*)alloc(1028 * 4);           // nbuck+1 (<=1025), real alloc
  unsigned short* w1t_hi = (unsigned short*)alloc(128 * 128 * 2);
  unsigned short* w1t_lo = (unsigned short*)alloc(128 * 128 * 2);
  unsigned short* wct_hi = (unsigned short*)alloc(128 * 128 * 2);
  unsigned short* wct_lo = (unsigned short*)alloc(128 * 128 * 2);
  float* bcat    = (float*)alloc(128 * 4);
  int2*  csr     = (int2*)alloc((size_t)E * 8);
  float* bufA    = (float*)alloc((size_t)N * 128 * 4);          // agg2 out (fp32)
  unsigned short* bufB = (unsigned short*)alloc((size_t)N * 128 * 2);  // hs1 bf16
  unsigned short* bufC = (unsigned short*)alloc((size_t)N * 128 * 2);  // out1 bf16

  const int nbuck = (N + 127) >> 7;               // 782 dst buckets of 128 nodes
  const int epb   = (E + NBLK - 1) / NBLK;        // edges per partition block

  // Aliased scratch (dead before its alias target is first written):
  //  - part (E int2 = 12.8MB) -> bufA   (bufA first written by agg2, much later)
  //  - G / tot                -> bufB   (bufB first written by gemm1, after build)
  int2* part = (int2*)bufA;
  int*  G    = (int*)bufB;                        // nbuck*NBLK ints = 3.2MB
  int*  tot  = (int*)((char*)bufB + (size_t)nbuck * NBLK * 4);

  float* out_mu = (float*)d_out;
  float* out_ls = out_mu + (size_t)N * 64;

  prep_wt<<<64, 256, 0, stream>>>(W1, w1t_hi, w1t_lo);
  prep_wcat_t<<<64, 256, 0, stream>>>(Wmu, Wls, bmu, bls, wct_hi, wct_lo, bcat);

  hist_coarse<<<NBLK, 256, 0, stream>>>(col, G, E, nbuck, epb);
  scan_bucket<<<nbuck, NBLK, 0, stream>>>(G, tot);
  scan_start<<<1, 1024, 0, stream>>>(tot, start, nbuck, E);
  partition_edges<<<NBLK, 256, 0, stream>>>(row, col, ea, G, start, part,
                                            E, nbuck, epb);
  bucket_prep<<<nbuck, 256, 0, stream>>>(start, part, csr, dinv, N);

  int gblocks = (N + 127) / 128;
  // hs1 = (x @ W1) * dinv[row]  -> permuted bf16
  gemm_mfma<<<gblocks, 256, 0, stream>>>(x, w1t_hi, w1t_lo, nullptr, dinv,
                                         nullptr, nullptr, bufB, 128, N);
  // out1 = dinv * relu(dinv[c]*(sum w*hs1[r] + hs1[c]) + b1) -> permuted bf16
  aggregate_lds<<<nbuck, 512, 0, stream>>>((const unsigned int*)bufB, start, csr,
                                           dinv, b1, (unsigned int*)bufC,
                                           nullptr, N, 1, 1);
  // agg2 = dinv[c]*(sum w*out1[r] + out1[c])  == A_norm @ h  -> fp32 (true order)
  aggregate_lds<<<nbuck, 512, 0, stream>>>((const unsigned int*)bufC, start, csr,
                                           dinv, nullptr, nullptr, bufA, N, 0, 0);
  // [mu | logstd] = agg2 @ [Wmu | Wls] + [bmu | bls]
  gemm_mfma<<<gblocks, 256, 0, stream>>>(bufA, wct_hi, wct_lo, bcat, nullptr,
                                         out_mu, out_ls, nullptr, 64, N);
}

// Round 5
// 289.539 us; speedup vs baseline: 9.7382x; 9.7371x over previous
//
#include <hip/hip_runtime.h>
#include <math.h>

// GCN-VGAE encoder, N=100000 nodes, E=1600000 edges, F=H=128, O=64 (fp32 in/out).
// Strategy (reverted to round-1 proven design + micro-opts):
//   - CSR build: two-level ATOMIC-FREE radix partition (global atomics on gfx950
//     write through at 32B/op; plain stores are L2-absorbed). Coarse partition
//     by col>>8 with LDS cursors, then per-bucket fine CSR build in LDS.
//     deg/dinv folded into build_fine via native ds_add_f32 (+lgkmcnt drain —
//     inline-asm DS ops are invisible to compiler waitcnt tracking).
//   - Aggregation: warp-gather (8 nodes x 32 lanes per block, bf16 rows,
//     batch-8 edges in flight). The LDS-tile SpMM experiment (rounds 2-4) was
//     20x slower (1344us vs 67us) at 2% HBM despite correct traffic — low
//     resident-wave count + LDS-atomic RMW path starve memory-level
//     parallelism. Reverted per pre-committed rule.
//   - Feature matrices bf16 (halves gather traffic). Symmetric norm factored:
//     pre-scale rows by dinv, aggregate RAW weights, post-scale by dinv[c].
//   - GEMMs on MFMA (16x16x32 bf16) with SPLIT precision: A=Ahi+Alo, W=Whi+Wlo,
//     C = Ahi*Whi + Alo*Whi + Ahi*Wlo  (error ~2^-18, fp32-grade).
//   - conv2/conv3 fused: agg2 = A_norm @ h once, then one GEMM with [Wmu|Wls].

#define NBLK 1024   // coarse-partition blocks; each handles ceil(E/NBLK) edges

typedef __attribute__((ext_vector_type(8))) short bf16x8;
typedef __attribute__((ext_vector_type(4))) float f32x4;

__device__ __forceinline__ unsigned short f2bf_rne(float f) {
  unsigned int u = __float_as_uint(f);
  u += 0x7FFFu + ((u >> 16) & 1u);
  return (unsigned short)(u >> 16);
}

__device__ __forceinline__ float bf2f(unsigned short h) {
  return __uint_as_float(((unsigned int)h) << 16);
}

__device__ __forceinline__ unsigned int pack2(unsigned short a, unsigned short b) {
  return (unsigned int)a | ((unsigned int)b << 16);
}

// Native fire-and-forget LDS float atomic add (ds byte address = low 32b of
// the generic pointer).
__device__ __forceinline__ void lds_fadd(float* addr, float v) {
  unsigned int off = (unsigned int)(size_t)addr;
  asm volatile("ds_add_f32 %0, %1" : : "v"(off), "v"(v) : "memory");
}

// Drain ALL outstanding DS ops (incl. inline-asm ones the compiler can't see).
// MUST precede any __syncthreads() that follows lds_fadd use.
__device__ __forceinline__ void ds_drain() {
  asm volatile("s_waitcnt lgkmcnt(0)" ::: "memory");
}

// ---------------- CSR build: two-level atomic-free partition ----------------

// Per-block LDS histogram over coarse buckets (col>>8). G[bucket][blk] layout.
__global__ __launch_bounds__(256) void hist_coarse(const int* __restrict__ col,
                                                   int* __restrict__ G,
                                                   int E, int nbuck, int epb) {
  __shared__ int h[512];
  int blk = blockIdx.x;
  for (int i = threadIdx.x; i < nbuck; i += 256) h[i] = 0;
  __syncthreads();
  int beg = blk * epb;
  int end = min(beg + epb, E);
  for (int p = beg + threadIdx.x; p < end; p += 256)
    atomicAdd(&h[col[p] >> 8], 1);
  __syncthreads();
  for (int i = threadIdx.x; i < nbuck; i += 256)
    G[(size_t)i * NBLK + blk] = h[i];
}

// Per-bucket exclusive scan over the NBLK block-counts; emits bucket totals.
__global__ __launch_bounds__(1024) void scan_bucket(int* __restrict__ G,
                                                    int* __restrict__ tot) {
  __shared__ int s[NBLK];
  int b = blockIdx.x;
  int v = G[(size_t)b * NBLK + threadIdx.x];
  s[threadIdx.x] = v;
  __syncthreads();
  for (int off = 1; off < NBLK; off <<= 1) {
    int t = (threadIdx.x >= off) ? s[threadIdx.x - off] : 0;
    __syncthreads();
    s[threadIdx.x] += t;
    __syncthreads();
  }
  G[(size_t)b * NBLK + threadIdx.x] = s[threadIdx.x] - v;   // exclusive
  if (threadIdx.x == NBLK - 1) tot[b] = s[NBLK - 1];
}

// Exclusive scan of bucket totals -> start[0..nbuck] (start[nbuck]=E).
__global__ __launch_bounds__(512) void scan_start(const int* __restrict__ tot,
                                                  int* __restrict__ start,
                                                  int* __restrict__ row_ptr,
                                                  int nbuck, int N, int E) {
  __shared__ int s[512];
  int v = (threadIdx.x < nbuck) ? tot[threadIdx.x] : 0;
  s[threadIdx.x] = v;
  __syncthreads();
  for (int off = 1; off < 512; off <<= 1) {
    int t = (threadIdx.x >= off) ? s[threadIdx.x - off] : 0;
    __syncthreads();
    s[threadIdx.x] += t;
    __syncthreads();
  }
  if (threadIdx.x < nbuck) start[threadIdx.x] = s[threadIdx.x] - v;
  if (threadIdx.x == 511) start[nbuck] = E;
  if (threadIdx.x == 0) row_ptr[N] = E;
}

// Coarse scatter: LDS cursors (start[b] + G[b][blk]); packs row|colLow into .x.
// All writes are plain stores (L2 write-back) — zero global atomics.
__global__ __launch_bounds__(256) void partition_edges(
    const int* __restrict__ row, const int* __restrict__ col,
    const float* __restrict__ w, const int* __restrict__ G,
    const int* __restrict__ start, int2* __restrict__ part,
    int E, int nbuck, int epb) {
  __shared__ int cur[512];
  int blk = blockIdx.x;
  for (int i = threadIdx.x; i < nbuck; i += 256)
    cur[i] = start[i] + G[(size_t)i * NBLK + blk];
  __syncthreads();
  int beg = blk * epb;
  int end = min(beg + epb, E);
  for (int p = beg + threadIdx.x; p < end; p += 256) {
    int c = col[p];
    int pos = atomicAdd(&cur[c >> 8], 1);             // LDS atomic (int, native)
    part[pos] = make_int2(row[p] | ((c & 255) << 17), // row < 2^17
                          __float_as_int(w[p]));
  }
}

// Fine build: one block per bucket (256 nodes). LDS hist + scan -> row_ptr and
// exact CSR slots; also accumulates deg (raw weight sum) -> dinv, saving a
// separate csr re-read pass.
__global__ __launch_bounds__(256) void build_fine(const int* __restrict__ start,
                                                  const int2* __restrict__ part,
                                                  int* __restrict__ row_ptr,
                                                  int2* __restrict__ csr,
                                                  float* __restrict__ dinv,
                                                  int N) {
  __shared__ int hist[256];
  __shared__ int sc[256];
  __shared__ int cur[256];
  __shared__ float deg[256];
  int b = blockIdx.x;
  int ebeg = start[b], eend = start[b + 1];
  hist[threadIdx.x] = 0;
  deg[threadIdx.x] = 0.f;
  __syncthreads();
  for (int p = ebeg + threadIdx.x; p < eend; p += 256) {
    int2 e = part[p];
    int dl = (e.x >> 17) & 255;
    atomicAdd(&hist[dl], 1);
    lds_fadd(&deg[dl], __int_as_float(e.y));
  }
  ds_drain();          // asm ds_add_f32 invisible to compiler waitcnt tracking
  __syncthreads();
  int v = hist[threadIdx.x];
  sc[threadIdx.x] = v;
  __syncthreads();
  for (int off = 1; off < 256; off <<= 1) {
    int t = (threadIdx.x >= off) ? sc[threadIdx.x - off] : 0;
    __syncthreads();
    sc[threadIdx.x] += t;
    __syncthreads();
  }
  int ex = sc[threadIdx.x] - v;   // exclusive
  int node = b * 256 + threadIdx.x;
  if (node < N) {
    row_ptr[node] = ebeg + ex;
    dinv[node] = 1.0f / sqrtf(1.0f + deg[threadIdx.x]);
  }
  cur[threadIdx.x] = ebeg + ex;
  __syncthreads();
  for (int p = ebeg + threadIdx.x; p < eend; p += 256) {
    int2 r = part[p];
    int pos = atomicAdd(&cur[(r.x >> 17) & 255], 1);       // LDS atomic (int)
    csr[pos] = make_int2(r.x & 0x1FFFF, r.y);
  }
}

// Transpose + bf16-split a 128x128 fp32 W: wt_hi/wt_lo[n][k] = split(W[k][n]).
__global__ void prep_wt(const float* __restrict__ Wsrc,
                        unsigned short* __restrict__ wt_hi,
                        unsigned short* __restrict__ wt_lo) {
  int i = blockIdx.x * blockDim.x + threadIdx.x;
  if (i >= 128 * 128) return;
  int n = i & 127, k = i >> 7;
  float f = Wsrc[(size_t)k * 128 + n];
  unsigned short h = f2bf_rne(f);
  unsigned short l = f2bf_rne(f - bf2f(h));
  wt_hi[(size_t)n * 128 + k] = h;
  wt_lo[(size_t)n * 128 + k] = l;
}

// Same for concatenated [Wmu | Wls] (each 128x64), plus bias concat.
__global__ void prep_wcat_t(const float* __restrict__ Wmu, const float* __restrict__ Wls,
                            const float* __restrict__ bmu, const float* __restrict__ bls,
                            unsigned short* __restrict__ wt_hi,
                            unsigned short* __restrict__ wt_lo,
                            float* __restrict__ bcat) {
  int i = blockIdx.x * blockDim.x + threadIdx.x;
  if (i >= 128 * 128) return;
  int n = i & 127, k = i >> 7;
  float f = (n < 64) ? Wmu[(size_t)k * 64 + n] : Wls[(size_t)k * 64 + (n - 64)];
  unsigned short h = f2bf_rne(f);
  unsigned short l = f2bf_rne(f - bf2f(h));
  wt_hi[(size_t)n * 128 + k] = h;
  wt_lo[(size_t)n * 128 + k] = l;
  if (i < 128) bcat[i] = (i < 64) ? bmu[i] : bls[i - 64];
}

// C[M,128] = (A[M,128] @ W[128,128]) * rowscale[row] + bias, via split-bf16 MFMA.
// WtHi/WtLo are bf16, TRANSPOSED [n][k]. Block: 256 thr = 4 waves, C-tile 128x128,
// wave computes 64x64 (4x4 tiles of 16x16). LDS XOR-swizzle: slot ^ (row&7).
// Output: fp32 split (C0 cols<split, C1 rest) and/or bf16 mirror Cbf (stride 128).
__global__ __launch_bounds__(256) void gemm_mfma(
    const float* __restrict__ A,
    const unsigned short* __restrict__ WtHi, const unsigned short* __restrict__ WtLo,
    const float* __restrict__ bias, const float* __restrict__ rowscale,
    float* __restrict__ C0, float* __restrict__ C1,
    unsigned short* __restrict__ Cbf, int split, int M) {
  __shared__ uint4 sAhi[1024];   // [row 0..127][slot 0..7] 16B slots, swizzled
  __shared__ uint4 sAlo[1024];
  __shared__ uint4 sWhi[1024];   // [col 0..127][slot 0..7]
  __shared__ uint4 sWlo[1024];

  int tid = threadIdx.x;
  int lane = tid & 63, wid = tid >> 6;
  int wave_r = (wid >> 1) * 64, wave_c = (wid & 1) * 64;
  int lrow = lane & 15, lkb = lane >> 4;   // lkb = k-chunk 0..3
  int rowBase = blockIdx.x * 128;

  f32x4 acc[4][4];
#pragma unroll
  for (int mr = 0; mr < 4; ++mr)
#pragma unroll
    for (int nc = 0; nc < 4; ++nc) acc[mr][nc] = (f32x4){0.f, 0.f, 0.f, 0.f};

  const uint4* WtHi4 = (const uint4*)WtHi;   // row = 16 uint4 (128 bf16)
  const uint4* WtLo4 = (const uint4*)WtLo;

  for (int kt = 0; kt < 128; kt += 64) {
    __syncthreads();
    // stage W tile: 128 cols x 64 k (bf16, already split) -> swizzled LDS
#pragma unroll
    for (int j = 0; j < 4; ++j) {
      int g = tid + 256 * j;            // 0..1023
      int c = g >> 3, k8 = g & 7;
      int slot = k8 ^ (c & 7);
      sWhi[c * 8 + slot] = WtHi4[c * 16 + (kt >> 3) + k8];
      sWlo[c * 8 + slot] = WtLo4[c * 16 + (kt >> 3) + k8];
    }
    // stage A tile: 128 rows x 64 k fp32 -> split hi/lo bf16 -> swizzled LDS
#pragma unroll
    for (int j = 0; j < 4; ++j) {
      int g = tid + 256 * j;            // 0..1023
      int r = g >> 3, k8 = g & 7;
      int grow = rowBase + r;
      float4 v0 = make_float4(0.f, 0.f, 0.f, 0.f);
      float4 v1 = v0;
      if (grow < M) {
        const float4* Ar = (const float4*)(A + (size_t)grow * 128 + kt);
        v0 = Ar[k8 * 2];
        v1 = Ar[k8 * 2 + 1];
      }
      float f[8] = {v0.x, v0.y, v0.z, v0.w, v1.x, v1.y, v1.z, v1.w};
      unsigned short h[8], l[8];
#pragma unroll
      for (int q = 0; q < 8; ++q) {
        h[q] = f2bf_rne(f[q]);
        l[q] = f2bf_rne(f[q] - bf2f(h[q]));
      }
      int slot = k8 ^ (r & 7);
      sAhi[r * 8 + slot] = make_uint4(pack2(h[0], h[1]), pack2(h[2], h[3]),
                                      pack2(h[4], h[5]), pack2(h[6], h[7]));
      sAlo[r * 8 + slot] = make_uint4(pack2(l[0], l[1]), pack2(l[2], l[3]),
                                      pack2(l[4], l[5]), pack2(l[6], l[7]));
    }
    __syncthreads();
    // compute: 2 MFMA k-steps (K=32 each) per LDS tile
#pragma unroll
    for (int ks = 0; ks < 2; ++ks) {
      bf16x8 ah[4], al[4], bh[4], bl[4];
#pragma unroll
      for (int mr = 0; mr < 4; ++mr) {
        int r = wave_r + mr * 16 + lrow;
        int slot = (ks * 4 + lkb) ^ (r & 7);
        ah[mr] = *(const bf16x8*)&sAhi[r * 8 + slot];
        al[mr] = *(const bf16x8*)&sAlo[r * 8 + slot];
      }
#pragma unroll
      for (int nc = 0; nc < 4; ++nc) {
        int c = wave_c + nc * 16 + lrow;
        int slot = (ks * 4 + lkb) ^ (c & 7);
        bh[nc] = *(const bf16x8*)&sWhi[c * 8 + slot];
        bl[nc] = *(const bf16x8*)&sWlo[c * 8 + slot];
      }
#pragma unroll
      for (int mr = 0; mr < 4; ++mr)
#pragma unroll
        for (int nc = 0; nc < 4; ++nc) {
          acc[mr][nc] = __builtin_amdgcn_mfma_f32_16x16x32_bf16(
              ah[mr], bh[nc], acc[mr][nc], 0, 0, 0);
          acc[mr][nc] = __builtin_amdgcn_mfma_f32_16x16x32_bf16(
              al[mr], bh[nc], acc[mr][nc], 0, 0, 0);
          acc[mr][nc] = __builtin_amdgcn_mfma_f32_16x16x32_bf16(
              ah[mr], bl[nc], acc[mr][nc], 0, 0, 0);
        }
    }
  }

  // epilogue: D[row=(lane>>4)*4+reg][col=lane&15] per 16x16 tile
#pragma unroll
  for (int mr = 0; mr < 4; ++mr) {
    int Rb = rowBase + wave_r + mr * 16 + lkb * 4;
    float sc[4];
#pragma unroll
    for (int reg = 0; reg < 4; ++reg)
      sc[reg] = (rowscale && (Rb + reg) < M) ? rowscale[Rb + reg] : 1.0f;
#pragma unroll
    for (int nc = 0; nc < 4; ++nc) {
      int c = wave_c + nc * 16 + lrow;
      float bb = bias ? bias[c] : 0.f;
      f32x4 v = acc[mr][nc];
#pragma unroll
      for (int reg = 0; reg < 4; ++reg) {
        int R = Rb + reg;
        if (R >= M) continue;
        float val = v[reg] * sc[reg] + bb;
        if (Cbf) Cbf[(size_t)R * 128 + c] = f2bf_rne(val);
        if (C0) {
          if (c < split) C0[(size_t)R * split + c] = val;
          else           C1[(size_t)R * split + (c - split)] = val;
        }
      }
    }
  }
}

// 256 threads = 8 nodes x 32 lanes; each lane owns 4 channels (ushort4 = 8B bf16).
// Batch-8 edges in flight per node for memory-level parallelism.
__global__ __launch_bounds__(256) void aggregate(
    const ushort4* __restrict__ hin, const int* __restrict__ row_ptr,
    const int2* __restrict__ csr, const float* __restrict__ dinv,
    const float4* __restrict__ bias4, ushort4* __restrict__ hout_bf,
    float4* __restrict__ hout_f4, int n, int do_relu, int scale_out) {
  int node = blockIdx.x * 8 + (threadIdx.x >> 5);
  if (node >= n) return;
  int t = threadIdx.x & 31;
  int beg = row_ptr[node], end = row_ptr[node + 1];
  ushort4 hs = hin[(size_t)node * 32 + t];   // self-loop (prescaled row)
  float4 acc = make_float4(bf2f(hs.x), bf2f(hs.y), bf2f(hs.z), bf2f(hs.w));
  int p = beg;
  for (; p + 8 <= end; p += 8) {
    int2 e[8];
    ushort4 h[8];
#pragma unroll
    for (int q = 0; q < 8; ++q) e[q] = csr[p + q];
#pragma unroll
    for (int q = 0; q < 8; ++q) h[q] = hin[(size_t)e[q].x * 32 + t];
#pragma unroll
    for (int q = 0; q < 8; ++q) {
      float wv = __int_as_float(e[q].y);
      acc.x = fmaf(wv, bf2f(h[q].x), acc.x);
      acc.y = fmaf(wv, bf2f(h[q].y), acc.y);
      acc.z = fmaf(wv, bf2f(h[q].z), acc.z);
      acc.w = fmaf(wv, bf2f(h[q].w), acc.w);
    }
  }
  for (; p < end; ++p) {
    int2 e = csr[p];
    ushort4 hv = hin[(size_t)e.x * 32 + t];
    float wv = __int_as_float(e.y);
    acc.x = fmaf(wv, bf2f(hv.x), acc.x); acc.y = fmaf(wv, bf2f(hv.y), acc.y);
    acc.z = fmaf(wv, bf2f(hv.z), acc.z); acc.w = fmaf(wv, bf2f(hv.w), acc.w);
  }
  float dc = dinv[node];
  float4 val = make_float4(dc * acc.x, dc * acc.y, dc * acc.z, dc * acc.w);
  if (bias4) {
    float4 b = bias4[t];
    val.x += b.x; val.y += b.y; val.z += b.z; val.w += b.w;
  }
  if (do_relu) {
    val.x = fmaxf(val.x, 0.f); val.y = fmaxf(val.y, 0.f);
    val.z = fmaxf(val.z, 0.f); val.w = fmaxf(val.w, 0.f);
  }
  if (scale_out) {
    val.x *= dc; val.y *= dc; val.z *= dc; val.w *= dc;
  }
  size_t o = (size_t)node * 32 + t;
  if (hout_bf) {
    ushort4 ov;
    ov.x = f2bf_rne(val.x); ov.y = f2bf_rne(val.y);
    ov.z = f2bf_rne(val.z); ov.w = f2bf_rne(val.w);
    hout_bf[o] = ov;
  }
  if (hout_f4) hout_f4[o] = val;
}

extern "C" void kernel_launch(void* const* d_in, const int* in_sizes, int n_in,
                              void* d_out, int out_size, void* d_ws, size_t ws_size,
                              hipStream_t stream) {
  const float* x   = (const float*)d_in[0];
  const int*   ei  = (const int*)d_in[1];
  const float* ea  = (const float*)d_in[2];
  const float* W1  = (const float*)d_in[3];
  const float* b1  = (const float*)d_in[4];
  const float* Wmu = (const float*)d_in[5];
  const float* bmu = (const float*)d_in[6];
  const float* Wls = (const float*)d_in[7];
  const float* bls = (const float*)d_in[8];
  const int N = in_sizes[0] / 128;
  const int E = in_sizes[2];
  const int* row = ei;
  const int* col = ei + E;

  char* p = (char*)d_ws;
  auto alloc = [&](size_t bytes) -> void* {
    void* r = (void*)p;
    p += (bytes + 255) & ~(size_t)255;
    return r;
  };
  float* dinv    = (float*)alloc((size_t)N * 4);
  int*   row_ptr = (int*)alloc((size_t)(N + 1) * 4);
  int*   start   = (int*)alloc(520 * 4);            // nbuck+1 (<=392)
  unsigned short* w1t_hi = (unsigned short*)alloc(128 * 128 * 2);
  unsigned short* w1t_lo = (unsigned short*)alloc(128 * 128 * 2);
  unsigned short* wct_hi = (unsigned short*)alloc(128 * 128 * 2);
  unsigned short* wct_lo = (unsigned short*)alloc(128 * 128 * 2);
  float* bcat    = (float*)alloc(128 * 4);
  int2*  csr     = (int2*)alloc((size_t)E * 8);
  float* bufA    = (float*)alloc((size_t)N * 128 * 4);          // agg2 out (fp32)
  unsigned short* bufB = (unsigned short*)alloc((size_t)N * 128 * 2);  // hs1 bf16
  unsigned short* bufC = (unsigned short*)alloc((size_t)N * 128 * 2);  // out1 bf16

  const int nbuck = (N + 255) >> 8;               // 391 coarse buckets (256 nodes)
  const int epb   = (E + NBLK - 1) / NBLK;        // edges per partition block

  // Aliased scratch (dead before its alias target is first written):
  //  - part (E int2 = 12.8MB) -> bufA   (bufA first written by agg2, much later)
  //  - G / tot                -> bufB   (bufB first written by gemm1, after build)
  int2* part = (int2*)bufA;
  int*  G    = (int*)bufB;                        // nbuck*NBLK ints = 1.6MB
  int*  tot  = (int*)((char*)bufB + (size_t)nbuck * NBLK * 4);

  float* out_mu = (float*)d_out;
  float* out_ls = out_mu + (size_t)N * 64;

  prep_wt<<<64, 256, 0, stream>>>(W1, w1t_hi, w1t_lo);
  prep_wcat_t<<<64, 256, 0, stream>>>(Wmu, Wls, bmu, bls, wct_hi, wct_lo, bcat);

  hist_coarse<<<NBLK, 256, 0, stream>>>(col, G, E, nbuck, epb);
  scan_bucket<<<nbuck, NBLK, 0, stream>>>(G, tot);
  scan_start<<<1, 512, 0, stream>>>(tot, start, row_ptr, nbuck, N, E);
  partition_edges<<<NBLK, 256, 0, stream>>>(row, col, ea, G, start, part,
                                            E, nbuck, epb);
  build_fine<<<nbuck, 256, 0, stream>>>(start, part, row_ptr, csr, dinv, N);

  int gblocks = (N + 127) / 128;
  int ablocks = (N + 7) / 8;
  // hs1 = (x @ W1) * dinv[row]  -> bf16 only
  gemm_mfma<<<gblocks, 256, 0, stream>>>(x, w1t_hi, w1t_lo, nullptr, dinv,
                                         nullptr, nullptr, bufB, 128, N);
  // out1 = dinv * relu(dinv[c]*(sum w*hs1[r] + hs1[c]) + b1) -> bf16 only
  aggregate<<<ablocks, 256, 0, stream>>>((const ushort4*)bufB, row_ptr, csr, dinv,
                                         (const float4*)b1, (ushort4*)bufC,
                                         nullptr, N, 1, 1);
  // agg2 = dinv[c]*(sum w*out1[r] + out1[c])  == A_norm @ h  -> fp32
  aggregate<<<ablocks, 256, 0, stream>>>((const ushort4*)bufC, row_ptr, csr, dinv,
                                         nullptr, nullptr, (float4*)bufA, N, 0, 0);
  // [mu | logstd] = agg2 @ [Wmu | Wls] + [bmu | bls]
  gemm_mfma<<<gblocks, 256, 0, stream>>>(bufA, wct_hi, wct_lo, bcat, nullptr,
                                         out_mu, out_ls, nullptr, 64, N);
}

// Round 6
// 280.920 us; speedup vs baseline: 10.0370x; 1.0307x over previous
//
#include <hip/hip_runtime.h>
#include <math.h>

// GCN-VGAE encoder, N=100000 nodes, E=1600000 edges, F=H=128, O=64 (fp32 in/out).
// Strategy:
//   - CSR build: two-level ATOMIC-FREE radix partition (global atomics on gfx950
//     write through at 32B/op; plain stores are L2-absorbed). Coarse partition
//     by col>>8 with LDS cursors, then per-bucket fine CSR build in LDS.
//     deg/dinv folded into build_fine via native ds_add_f32 (+lgkmcnt drain —
//     inline-asm DS ops are invisible to compiler waitcnt tracking).
//   - Aggregation: warp-gather, 8 nodes x 32 lanes per block, bf16 rows,
//     BATCH-4 edges in flight (batch-8 raised VGPR 24->36, occupancy 70->60%,
//     and regressed 67->72.6us — round-5 lesson: the pass is concurrency-
//     saturated; occupancy beats per-wave batching).
//     The LDS-tile SpMM experiment (rounds 2-4) was 20x slower at 2% HBM
//     despite correct traffic — reverted per pre-committed rule.
//   - Feature matrices bf16 (halves gather traffic). Symmetric norm factored:
//     pre-scale rows by dinv, aggregate RAW weights, post-scale by dinv[c].
//   - GEMMs on MFMA (16x16x32 bf16) with SPLIT precision: A=Ahi+Alo, W=Whi+Wlo,
//     C = Ahi*Whi + Alo*Whi + Ahi*Wlo  (error ~2^-18, fp32-grade).
//   - conv2/conv3 fused: agg2 = A_norm @ h once, then one GEMM with [Wmu|Wls].

#define NBLK 1024   // coarse-partition blocks; each handles ceil(E/NBLK) edges

typedef __attribute__((ext_vector_type(8))) short bf16x8;
typedef __attribute__((ext_vector_type(4))) float f32x4;

__device__ __forceinline__ unsigned short f2bf_rne(float f) {
  unsigned int u = __float_as_uint(f);
  u += 0x7FFFu + ((u >> 16) & 1u);
  return (unsigned short)(u >> 16);
}

__device__ __forceinline__ float bf2f(unsigned short h) {
  return __uint_as_float(((unsigned int)h) << 16);
}

__device__ __forceinline__ unsigned int pack2(unsigned short a, unsigned short b) {
  return (unsigned int)a | ((unsigned int)b << 16);
}

// Native fire-and-forget LDS float atomic add (ds byte address = low 32b of
// the generic pointer).
__device__ __forceinline__ void lds_fadd(float* addr, float v) {
  unsigned int off = (unsigned int)(size_t)addr;
  asm volatile("ds_add_f32 %0, %1" : : "v"(off), "v"(v) : "memory");
}

// Drain ALL outstanding DS ops (incl. inline-asm ones the compiler can't see).
// MUST precede any __syncthreads() that follows lds_fadd use.
__device__ __forceinline__ void ds_drain() {
  asm volatile("s_waitcnt lgkmcnt(0)" ::: "memory");
}

// ---------------- CSR build: two-level atomic-free partition ----------------

// Per-block LDS histogram over coarse buckets (col>>8). G[bucket][blk] layout.
__global__ __launch_bounds__(256) void hist_coarse(const int* __restrict__ col,
                                                   int* __restrict__ G,
                                                   int E, int nbuck, int epb) {
  __shared__ int h[512];
  int blk = blockIdx.x;
  for (int i = threadIdx.x; i < nbuck; i += 256) h[i] = 0;
  __syncthreads();
  int beg = blk * epb;
  int end = min(beg + epb, E);
  for (int p = beg + threadIdx.x; p < end; p += 256)
    atomicAdd(&h[col[p] >> 8], 1);
  __syncthreads();
  for (int i = threadIdx.x; i < nbuck; i += 256)
    G[(size_t)i * NBLK + blk] = h[i];
}

// Per-bucket exclusive scan over the NBLK block-counts; emits bucket totals.
__global__ __launch_bounds__(1024) void scan_bucket(int* __restrict__ G,
                                                    int* __restrict__ tot) {
  __shared__ int s[NBLK];
  int b = blockIdx.x;
  int v = G[(size_t)b * NBLK + threadIdx.x];
  s[threadIdx.x] = v;
  __syncthreads();
  for (int off = 1; off < NBLK; off <<= 1) {
    int t = (threadIdx.x >= off) ? s[threadIdx.x - off] : 0;
    __syncthreads();
    s[threadIdx.x] += t;
    __syncthreads();
  }
  G[(size_t)b * NBLK + threadIdx.x] = s[threadIdx.x] - v;   // exclusive
  if (threadIdx.x == NBLK - 1) tot[b] = s[NBLK - 1];
}

// Exclusive scan of bucket totals -> start[0..nbuck] (start[nbuck]=E).
__global__ __launch_bounds__(512) void scan_start(const int* __restrict__ tot,
                                                  int* __restrict__ start,
                                                  int* __restrict__ row_ptr,
                                                  int nbuck, int N, int E) {
  __shared__ int s[512];
  int v = (threadIdx.x < nbuck) ? tot[threadIdx.x] : 0;
  s[threadIdx.x] = v;
  __syncthreads();
  for (int off = 1; off < 512; off <<= 1) {
    int t = (threadIdx.x >= off) ? s[threadIdx.x - off] : 0;
    __syncthreads();
    s[threadIdx.x] += t;
    __syncthreads();
  }
  if (threadIdx.x < nbuck) start[threadIdx.x] = s[threadIdx.x] - v;
  if (threadIdx.x == 511) start[nbuck] = E;
  if (threadIdx.x == 0) row_ptr[N] = E;
}

// Coarse scatter: LDS cursors (start[b] + G[b][blk]); packs row|colLow into .x.
// All writes are plain stores (L2 write-back) — zero global atomics.
__global__ __launch_bounds__(256) void partition_edges(
    const int* __restrict__ row, const int* __restrict__ col,
    const float* __restrict__ w, const int* __restrict__ G,
    const int* __restrict__ start, int2* __restrict__ part,
    int E, int nbuck, int epb) {
  __shared__ int cur[512];
  int blk = blockIdx.x;
  for (int i = threadIdx.x; i < nbuck; i += 256)
    cur[i] = start[i] + G[(size_t)i * NBLK + blk];
  __syncthreads();
  int beg = blk * epb;
  int end = min(beg + epb, E);
  for (int p = beg + threadIdx.x; p < end; p += 256) {
    int c = col[p];
    int pos = atomicAdd(&cur[c >> 8], 1);             // LDS atomic (int, native)
    part[pos] = make_int2(row[p] | ((c & 255) << 17), // row < 2^17
                          __float_as_int(w[p]));
  }
}

// Fine build: one block per bucket (256 nodes). LDS hist + scan -> row_ptr and
// exact CSR slots; also accumulates deg (raw weight sum) -> dinv, saving a
// separate csr re-read pass.
__global__ __launch_bounds__(256) void build_fine(const int* __restrict__ start,
                                                  const int2* __restrict__ part,
                                                  int* __restrict__ row_ptr,
                                                  int2* __restrict__ csr,
                                                  float* __restrict__ dinv,
                                                  int N) {
  __shared__ int hist[256];
  __shared__ int sc[256];
  __shared__ int cur[256];
  __shared__ float deg[256];
  int b = blockIdx.x;
  int ebeg = start[b], eend = start[b + 1];
  hist[threadIdx.x] = 0;
  deg[threadIdx.x] = 0.f;
  __syncthreads();
  for (int p = ebeg + threadIdx.x; p < eend; p += 256) {
    int2 e = part[p];
    int dl = (e.x >> 17) & 255;
    atomicAdd(&hist[dl], 1);
    lds_fadd(&deg[dl], __int_as_float(e.y));
  }
  ds_drain();          // asm ds_add_f32 invisible to compiler waitcnt tracking
  __syncthreads();
  int v = hist[threadIdx.x];
  sc[threadIdx.x] = v;
  __syncthreads();
  for (int off = 1; off < 256; off <<= 1) {
    int t = (threadIdx.x >= off) ? sc[threadIdx.x - off] : 0;
    __syncthreads();
    sc[threadIdx.x] += t;
    __syncthreads();
  }
  int ex = sc[threadIdx.x] - v;   // exclusive
  int node = b * 256 + threadIdx.x;
  if (node < N) {
    row_ptr[node] = ebeg + ex;
    dinv[node] = 1.0f / sqrtf(1.0f + deg[threadIdx.x]);
  }
  cur[threadIdx.x] = ebeg + ex;
  __syncthreads();
  for (int p = ebeg + threadIdx.x; p < eend; p += 256) {
    int2 r = part[p];
    int pos = atomicAdd(&cur[(r.x >> 17) & 255], 1);       // LDS atomic (int)
    csr[pos] = make_int2(r.x & 0x1FFFF, r.y);
  }
}

// Transpose + bf16-split a 128x128 fp32 W: wt_hi/wt_lo[n][k] = split(W[k][n]).
__global__ void prep_wt(const float* __restrict__ Wsrc,
                        unsigned short* __restrict__ wt_hi,
                        unsigned short* __restrict__ wt_lo) {
  int i = blockIdx.x * blockDim.x + threadIdx.x;
  if (i >= 128 * 128) return;
  int n = i & 127, k = i >> 7;
  float f = Wsrc[(size_t)k * 128 + n];
  unsigned short h = f2bf_rne(f);
  unsigned short l = f2bf_rne(f - bf2f(h));
  wt_hi[(size_t)n * 128 + k] = h;
  wt_lo[(size_t)n * 128 + k] = l;
}

// Same for concatenated [Wmu | Wls] (each 128x64), plus bias concat.
__global__ void prep_wcat_t(const float* __restrict__ Wmu, const float* __restrict__ Wls,
                            const float* __restrict__ bmu, const float* __restrict__ bls,
                            unsigned short* __restrict__ wt_hi,
                            unsigned short* __restrict__ wt_lo,
                            float* __restrict__ bcat) {
  int i = blockIdx.x * blockDim.x + threadIdx.x;
  if (i >= 128 * 128) return;
  int n = i & 127, k = i >> 7;
  float f = (n < 64) ? Wmu[(size_t)k * 64 + n] : Wls[(size_t)k * 64 + (n - 64)];
  unsigned short h = f2bf_rne(f);
  unsigned short l = f2bf_rne(f - bf2f(h));
  wt_hi[(size_t)n * 128 + k] = h;
  wt_lo[(size_t)n * 128 + k] = l;
  if (i < 128) bcat[i] = (i < 64) ? bmu[i] : bls[i - 64];
}

// C[M,128] = (A[M,128] @ W[128,128]) * rowscale[row] + bias, via split-bf16 MFMA.
// WtHi/WtLo are bf16, TRANSPOSED [n][k]. Block: 256 thr = 4 waves, C-tile 128x128,
// wave computes 64x64 (4x4 tiles of 16x16). LDS XOR-swizzle: slot ^ (row&7).
// Output: fp32 split (C0 cols<split, C1 rest) and/or bf16 mirror Cbf (stride 128).
__global__ __launch_bounds__(256) void gemm_mfma(
    const float* __restrict__ A,
    const unsigned short* __restrict__ WtHi, const unsigned short* __restrict__ WtLo,
    const float* __restrict__ bias, const float* __restrict__ rowscale,
    float* __restrict__ C0, float* __restrict__ C1,
    unsigned short* __restrict__ Cbf, int split, int M) {
  __shared__ uint4 sAhi[1024];   // [row 0..127][slot 0..7] 16B slots, swizzled
  __shared__ uint4 sAlo[1024];
  __shared__ uint4 sWhi[1024];   // [col 0..127][slot 0..7]
  __shared__ uint4 sWlo[1024];

  int tid = threadIdx.x;
  int lane = tid & 63, wid = tid >> 6;
  int wave_r = (wid >> 1) * 64, wave_c = (wid & 1) * 64;
  int lrow = lane & 15, lkb = lane >> 4;   // lkb = k-chunk 0..3
  int rowBase = blockIdx.x * 128;

  f32x4 acc[4][4];
#pragma unroll
  for (int mr = 0; mr < 4; ++mr)
#pragma unroll
    for (int nc = 0; nc < 4; ++nc) acc[mr][nc] = (f32x4){0.f, 0.f, 0.f, 0.f};

  const uint4* WtHi4 = (const uint4*)WtHi;   // row = 16 uint4 (128 bf16)
  const uint4* WtLo4 = (const uint4*)WtLo;

  for (int kt = 0; kt < 128; kt += 64) {
    __syncthreads();
    // stage W tile: 128 cols x 64 k (bf16, already split) -> swizzled LDS
#pragma unroll
    for (int j = 0; j < 4; ++j) {
      int g = tid + 256 * j;            // 0..1023
      int c = g >> 3, k8 = g & 7;
      int slot = k8 ^ (c & 7);
      sWhi[c * 8 + slot] = WtHi4[c * 16 + (kt >> 3) + k8];
      sWlo[c * 8 + slot] = WtLo4[c * 16 + (kt >> 3) + k8];
    }
    // stage A tile: 128 rows x 64 k fp32 -> split hi/lo bf16 -> swizzled LDS
#pragma unroll
    for (int j = 0; j < 4; ++j) {
      int g = tid + 256 * j;            // 0..1023
      int r = g >> 3, k8 = g & 7;
      int grow = rowBase + r;
      float4 v0 = make_float4(0.f, 0.f, 0.f, 0.f);
      float4 v1 = v0;
      if (grow < M) {
        const float4* Ar = (const float4*)(A + (size_t)grow * 128 + kt);
        v0 = Ar[k8 * 2];
        v1 = Ar[k8 * 2 + 1];
      }
      float f[8] = {v0.x, v0.y, v0.z, v0.w, v1.x, v1.y, v1.z, v1.w};
      unsigned short h[8], l[8];
#pragma unroll
      for (int q = 0; q < 8; ++q) {
        h[q] = f2bf_rne(f[q]);
        l[q] = f2bf_rne(f[q] - bf2f(h[q]));
      }
      int slot = k8 ^ (r & 7);
      sAhi[r * 8 + slot] = make_uint4(pack2(h[0], h[1]), pack2(h[2], h[3]),
                                      pack2(h[4], h[5]), pack2(h[6], h[7]));
      sAlo[r * 8 + slot] = make_uint4(pack2(l[0], l[1]), pack2(l[2], l[3]),
                                      pack2(l[4], l[5]), pack2(l[6], l[7]));
    }
    __syncthreads();
    // compute: 2 MFMA k-steps (K=32 each) per LDS tile
#pragma unroll
    for (int ks = 0; ks < 2; ++ks) {
      bf16x8 ah[4], al[4], bh[4], bl[4];
#pragma unroll
      for (int mr = 0; mr < 4; ++mr) {
        int r = wave_r + mr * 16 + lrow;
        int slot = (ks * 4 + lkb) ^ (r & 7);
        ah[mr] = *(const bf16x8*)&sAhi[r * 8 + slot];
        al[mr] = *(const bf16x8*)&sAlo[r * 8 + slot];
      }
#pragma unroll
      for (int nc = 0; nc < 4; ++nc) {
        int c = wave_c + nc * 16 + lrow;
        int slot = (ks * 4 + lkb) ^ (c & 7);
        bh[nc] = *(const bf16x8*)&sWhi[c * 8 + slot];
        bl[nc] = *(const bf16x8*)&sWlo[c * 8 + slot];
      }
#pragma unroll
      for (int mr = 0; mr < 4; ++mr)
#pragma unroll
        for (int nc = 0; nc < 4; ++nc) {
          acc[mr][nc] = __builtin_amdgcn_mfma_f32_16x16x32_bf16(
              ah[mr], bh[nc], acc[mr][nc], 0, 0, 0);
          acc[mr][nc] = __builtin_amdgcn_mfma_f32_16x16x32_bf16(
              al[mr], bh[nc], acc[mr][nc], 0, 0, 0);
          acc[mr][nc] = __builtin_amdgcn_mfma_f32_16x16x32_bf16(
              ah[mr], bl[nc], acc[mr][nc], 0, 0, 0);
        }
    }
  }

  // epilogue: D[row=(lane>>4)*4+reg][col=lane&15] per 16x16 tile
#pragma unroll
  for (int mr = 0; mr < 4; ++mr) {
    int Rb = rowBase + wave_r + mr * 16 + lkb * 4;
    float sc[4];
#pragma unroll
    for (int reg = 0; reg < 4; ++reg)
      sc[reg] = (rowscale && (Rb + reg) < M) ? rowscale[Rb + reg] : 1.0f;
#pragma unroll
    for (int nc = 0; nc < 4; ++nc) {
      int c = wave_c + nc * 16 + lrow;
      float bb = bias ? bias[c] : 0.f;
      f32x4 v = acc[mr][nc];
#pragma unroll
      for (int reg = 0; reg < 4; ++reg) {
        int R = Rb + reg;
        if (R >= M) continue;
        float val = v[reg] * sc[reg] + bb;
        if (Cbf) Cbf[(size_t)R * 128 + c] = f2bf_rne(val);
        if (C0) {
          if (c < split) C0[(size_t)R * split + c] = val;
          else           C1[(size_t)R * split + (c - split)] = val;
        }
      }
    }
  }
}

// 256 threads = 8 nodes x 32 lanes; each lane owns 4 channels (ushort4 = 8B bf16).
// Batch-4 edges in flight (proven optimum: 24 VGPR, ~70% occupancy).
__global__ __launch_bounds__(256) void aggregate(
    const ushort4* __restrict__ hin, const int* __restrict__ row_ptr,
    const int2* __restrict__ csr, const float* __restrict__ dinv,
    const float4* __restrict__ bias4, ushort4* __restrict__ hout_bf,
    float4* __restrict__ hout_f4, int n, int do_relu, int scale_out) {
  int node = blockIdx.x * 8 + (threadIdx.x >> 5);
  if (node >= n) return;
  int t = threadIdx.x & 31;
  int beg = row_ptr[node], end = row_ptr[node + 1];
  ushort4 hs = hin[(size_t)node * 32 + t];   // self-loop (prescaled row)
  float4 acc = make_float4(bf2f(hs.x), bf2f(hs.y), bf2f(hs.z), bf2f(hs.w));
  int p = beg;
  for (; p + 4 <= end; p += 4) {
    int2 e0 = csr[p + 0];
    int2 e1 = csr[p + 1];
    int2 e2 = csr[p + 2];
    int2 e3 = csr[p + 3];
    ushort4 h0 = hin[(size_t)e0.x * 32 + t];
    ushort4 h1 = hin[(size_t)e1.x * 32 + t];
    ushort4 h2 = hin[(size_t)e2.x * 32 + t];
    ushort4 h3 = hin[(size_t)e3.x * 32 + t];
    float w0 = __int_as_float(e0.y), w1 = __int_as_float(e1.y);
    float w2 = __int_as_float(e2.y), w3 = __int_as_float(e3.y);
    acc.x = fmaf(w0, bf2f(h0.x), acc.x); acc.y = fmaf(w0, bf2f(h0.y), acc.y);
    acc.z = fmaf(w0, bf2f(h0.z), acc.z); acc.w = fmaf(w0, bf2f(h0.w), acc.w);
    acc.x = fmaf(w1, bf2f(h1.x), acc.x); acc.y = fmaf(w1, bf2f(h1.y), acc.y);
    acc.z = fmaf(w1, bf2f(h1.z), acc.z); acc.w = fmaf(w1, bf2f(h1.w), acc.w);
    acc.x = fmaf(w2, bf2f(h2.x), acc.x); acc.y = fmaf(w2, bf2f(h2.y), acc.y);
    acc.z = fmaf(w2, bf2f(h2.z), acc.z); acc.w = fmaf(w2, bf2f(h2.w), acc.w);
    acc.x = fmaf(w3, bf2f(h3.x), acc.x); acc.y = fmaf(w3, bf2f(h3.y), acc.y);
    acc.z = fmaf(w3, bf2f(h3.z), acc.z); acc.w = fmaf(w3, bf2f(h3.w), acc.w);
  }
  for (; p < end; ++p) {
    int2 e = csr[p];
    ushort4 hv = hin[(size_t)e.x * 32 + t];
    float wv = __int_as_float(e.y);
    acc.x = fmaf(wv, bf2f(hv.x), acc.x); acc.y = fmaf(wv, bf2f(hv.y), acc.y);
    acc.z = fmaf(wv, bf2f(hv.z), acc.z); acc.w = fmaf(wv, bf2f(hv.w), acc.w);
  }
  float dc = dinv[node];
  float4 val = make_float4(dc * acc.x, dc * acc.y, dc * acc.z, dc * acc.w);
  if (bias4) {
    float4 b = bias4[t];
    val.x += b.x; val.y += b.y; val.z += b.z; val.w += b.w;
  }
  if (do_relu) {
    val.x = fmaxf(val.x, 0.f); val.y = fmaxf(val.y, 0.f);
    val.z = fmaxf(val.z, 0.f); val.w = fmaxf(val.w, 0.f);
  }
  if (scale_out) {
    val.x *= dc; val.y *= dc; val.z *= dc; val.w *= dc;
  }
  size_t o = (size_t)node * 32 + t;
  if (hout_bf) {
    ushort4 ov;
    ov.x = f2bf_rne(val.x); ov.y = f2bf_rne(val.y);
    ov.z = f2bf_rne(val.z); ov.w = f2bf_rne(val.w);
    hout_bf[o] = ov;
  }
  if (hout_f4) hout_f4[o] = val;
}

extern "C" void kernel_launch(void* const* d_in, const int* in_sizes, int n_in,
                              void* d_out, int out_size, void* d_ws, size_t ws_size,
                              hipStream_t stream) {
  const float* x   = (const float*)d_in[0];
  const int*   ei  = (const int*)d_in[1];
  const float* ea  = (const float*)d_in[2];
  const float* W1  = (const float*)d_in[3];
  const float* b1  = (const float*)d_in[4];
  const float* Wmu = (const float*)d_in[5];
  const float* bmu = (const float*)d_in[6];
  const float* Wls = (const float*)d_in[7];
  const float* bls = (const float*)d_in[8];
  const int N = in_sizes[0] / 128;
  const int E = in_sizes[2];
  const int* row = ei;
  const int* col = ei + E;

  char* p = (char*)d_ws;
  auto alloc = [&](size_t bytes) -> void* {
    void* r = (void*)p;
    p += (bytes + 255) & ~(size_t)255;
    return r;
  };
  float* dinv    = (float*)alloc((size_t)N * 4);
  int*   row_ptr = (int*)alloc((size_t)(N + 1) * 4);
  int*   start   = (int*)alloc(520 * 4);            // nbuck+1 (<=392)
  unsigned short* w1t_hi = (unsigned short*)alloc(128 * 128 * 2);
  unsigned short* w1t_lo = (unsigned short*)alloc(128 * 128 * 2);
  unsigned short* wct_hi = (unsigned short*)alloc(128 * 128 * 2);
  unsigned short* wct_lo = (unsigned short*)alloc(128 * 128 * 2);
  float* bcat    = (float*)alloc(128 * 4);
  int2*  csr     = (int2*)alloc((size_t)E * 8);
  float* bufA    = (float*)alloc((size_t)N * 128 * 4);          // agg2 out (fp32)
  unsigned short* bufB = (unsigned short*)alloc((size_t)N * 128 * 2);  // hs1 bf16
  unsigned short* bufC = (unsigned short*)alloc((size_t)N * 128 * 2);  // out1 bf16

  const int nbuck = (N + 255) >> 8;               // 391 coarse buckets (256 nodes)
  const int epb   = (E + NBLK - 1) / NBLK;        // edges per partition block

  // Aliased scratch (dead before its alias target is first written):
  //  - part (E int2 = 12.8MB) -> bufA   (bufA first written by agg2, much later)
  //  - G / tot                -> bufB   (bufB first written by gemm1, after build)
  int2* part = (int2*)bufA;
  int*  G    = (int*)bufB;                        // nbuck*NBLK ints = 1.6MB
  int*  tot  = (int*)((char*)bufB + (size_t)nbuck * NBLK * 4);

  float* out_mu = (float*)d_out;
  float* out_ls = out_mu + (size_t)N * 64;

  prep_wt<<<64, 256, 0, stream>>>(W1, w1t_hi, w1t_lo);
  prep_wcat_t<<<64, 256, 0, stream>>>(Wmu, Wls, bmu, bls, wct_hi, wct_lo, bcat);

  hist_coarse<<<NBLK, 256, 0, stream>>>(col, G, E, nbuck, epb);
  scan_bucket<<<nbuck, NBLK, 0, stream>>>(G, tot);
  scan_start<<<1, 512, 0, stream>>>(tot, start, row_ptr, nbuck, N, E);
  partition_edges<<<NBLK, 256, 0, stream>>>(row, col, ea, G, start, part,
                                            E, nbuck, epb);
  build_fine<<<nbuck, 256, 0, stream>>>(start, part, row_ptr, csr, dinv, N);

  int gblocks = (N + 127) / 128;
  int ablocks = (N + 7) / 8;
  // hs1 = (x @ W1) * dinv[row]  -> bf16 only
  gemm_mfma<<<gblocks, 256, 0, stream>>>(x, w1t_hi, w1t_lo, nullptr, dinv,
                                         nullptr, nullptr, bufB, 128, N);
  // out1 = dinv * relu(dinv[c]*(sum w*hs1[r] + hs1[c]) + b1) -> bf16 only
  aggregate<<<ablocks, 256, 0, stream>>>((const ushort4*)bufB, row_ptr, csr, dinv,
                                         (const float4*)b1, (ushort4*)bufC,
                                         nullptr, N, 1, 1);
  // agg2 = dinv[c]*(sum w*out1[r] + out1[c])  == A_norm @ h  -> fp32
  aggregate<<<ablocks, 256, 0, stream>>>((const ushort4*)bufC, row_ptr, csr, dinv,
                                         nullptr, nullptr, (float4*)bufA, N, 0, 0);
  // [mu | logstd] = agg2 @ [Wmu | Wls] + [bmu | bls]
  gemm_mfma<<<gblocks, 256, 0, stream>>>(bufA, wct_hi, wct_lo, bcat, nullptr,
                                         out_mu, out_ls, nullptr, 64, N);
}

// Round 7
// 272.063 us; speedup vs baseline: 10.3637x; 1.0326x over previous
//
#include <hip/hip_runtime.h>
#include <math.h>

// GCN-VGAE encoder, N=100000 nodes, E=1600000 edges, F=H=128, O=64 (fp32 in/out).
// Strategy:
//   - CSR build: two-level ATOMIC-FREE radix partition (global atomics on gfx950
//     write through at 32B/op; plain stores are L2-absorbed). Coarse partition
//     by col>>8 with LDS cursors, then per-bucket fine CSR build in LDS.
//     deg/dinv folded into build_fine via native ds_add_f32 (+lgkmcnt drain —
//     inline-asm DS ops are invisible to compiler waitcnt tracking).
//   - Aggregation: warp-gather, 8 nodes x 32 lanes per block, bf16 rows,
//     BATCH-4 edges in flight (batch-8 raised VGPR 24->36, occupancy 70->60%,
//     regressed — occupancy beats per-wave batching on this fabric-bound pass).
//     Aggregate pair is at the structural floor: FETCH 194MB = compulsory
//     8-XCD re-fetch of the 25.6MB bf16 table at ~2.9 TB/s fabric service.
//     (LDS-tile SpMM experiment rounds 2-4: 20x slower, reverted.)
//   - agg2 epilogue emits PRESPLIT hi/lo bf16 planes (VALU hidden under fabric
//     stalls); gemm2's A-staging becomes a pure copy — no fp32 split VALU.
//   - Feature matrices bf16 (halves gather traffic). Symmetric norm factored:
//     pre-scale rows by dinv, aggregate RAW weights, post-scale by dinv[c].
//   - GEMMs on MFMA (16x16x32 bf16) with SPLIT precision: A=Ahi+Alo, W=Whi+Wlo,
//     C = Ahi*Whi + Alo*Whi + Ahi*Wlo  (error ~2^-18, fp32-grade).
//   - conv2/conv3 fused: agg2 = A_norm @ h once, then one GEMM with [Wmu|Wls].

#define NBLK 512    // coarse-partition blocks; each handles ceil(E/NBLK) edges

typedef __attribute__((ext_vector_type(8))) short bf16x8;
typedef __attribute__((ext_vector_type(4))) float f32x4;

__device__ __forceinline__ unsigned short f2bf_rne(float f) {
  unsigned int u = __float_as_uint(f);
  u += 0x7FFFu + ((u >> 16) & 1u);
  return (unsigned short)(u >> 16);
}

__device__ __forceinline__ float bf2f(unsigned short h) {
  return __uint_as_float(((unsigned int)h) << 16);
}

__device__ __forceinline__ unsigned int pack2(unsigned short a, unsigned short b) {
  return (unsigned int)a | ((unsigned int)b << 16);
}

// Native fire-and-forget LDS float atomic add (ds byte address = low 32b of
// the generic pointer).
__device__ __forceinline__ void lds_fadd(float* addr, float v) {
  unsigned int off = (unsigned int)(size_t)addr;
  asm volatile("ds_add_f32 %0, %1" : : "v"(off), "v"(v) : "memory");
}

// Drain ALL outstanding DS ops (incl. inline-asm ones the compiler can't see).
// MUST precede any __syncthreads() that follows lds_fadd use.
__device__ __forceinline__ void ds_drain() {
  asm volatile("s_waitcnt lgkmcnt(0)" ::: "memory");
}

// ---------------- CSR build: two-level atomic-free partition ----------------

// Per-block LDS histogram over coarse buckets (col>>8). G[bucket][blk] layout.
__global__ __launch_bounds__(256) void hist_coarse(const int* __restrict__ col,
                                                   int* __restrict__ G,
                                                   int E, int nbuck, int epb) {
  __shared__ int h[512];
  int blk = blockIdx.x;
  for (int i = threadIdx.x; i < nbuck; i += 256) h[i] = 0;
  __syncthreads();
  int beg = blk * epb;
  int end = min(beg + epb, E);
  for (int p = beg + threadIdx.x; p < end; p += 256)
    atomicAdd(&h[col[p] >> 8], 1);
  __syncthreads();
  for (int i = threadIdx.x; i < nbuck; i += 256)
    G[(size_t)i * NBLK + blk] = h[i];
}

// Per-bucket exclusive scan over the NBLK block-counts; emits bucket totals.
__global__ __launch_bounds__(NBLK) void scan_bucket(int* __restrict__ G,
                                                    int* __restrict__ tot) {
  __shared__ int s[NBLK];
  int b = blockIdx.x;
  int v = G[(size_t)b * NBLK + threadIdx.x];
  s[threadIdx.x] = v;
  __syncthreads();
  for (int off = 1; off < NBLK; off <<= 1) {
    int t = (threadIdx.x >= off) ? s[threadIdx.x - off] : 0;
    __syncthreads();
    s[threadIdx.x] += t;
    __syncthreads();
  }
  G[(size_t)b * NBLK + threadIdx.x] = s[threadIdx.x] - v;   // exclusive
  if (threadIdx.x == NBLK - 1) tot[b] = s[NBLK - 1];
}

// Exclusive scan of bucket totals -> start[0..nbuck] (start[nbuck]=E).
__global__ __launch_bounds__(512) void scan_start(const int* __restrict__ tot,
                                                  int* __restrict__ start,
                                                  int* __restrict__ row_ptr,
                                                  int nbuck, int N, int E) {
  __shared__ int s[512];
  int v = (threadIdx.x < nbuck) ? tot[threadIdx.x] : 0;
  s[threadIdx.x] = v;
  __syncthreads();
  for (int off = 1; off < 512; off <<= 1) {
    int t = (threadIdx.x >= off) ? s[threadIdx.x - off] : 0;
    __syncthreads();
    s[threadIdx.x] += t;
    __syncthreads();
  }
  if (threadIdx.x < nbuck) start[threadIdx.x] = s[threadIdx.x] - v;
  if (threadIdx.x == 511) start[nbuck] = E;
  if (threadIdx.x == 0) row_ptr[N] = E;
}

// Coarse scatter: LDS cursors (start[b] + G[b][blk]); packs row|colLow into .x.
// All writes are plain stores (L2 write-back) — zero global atomics.
__global__ __launch_bounds__(256) void partition_edges(
    const int* __restrict__ row, const int* __restrict__ col,
    const float* __restrict__ w, const int* __restrict__ G,
    const int* __restrict__ start, int2* __restrict__ part,
    int E, int nbuck, int epb) {
  __shared__ int cur[512];
  int blk = blockIdx.x;
  for (int i = threadIdx.x; i < nbuck; i += 256)
    cur[i] = start[i] + G[(size_t)i * NBLK + blk];
  __syncthreads();
  int beg = blk * epb;
  int end = min(beg + epb, E);
  for (int p = beg + threadIdx.x; p < end; p += 256) {
    int c = col[p];
    int pos = atomicAdd(&cur[c >> 8], 1);             // LDS atomic (int, native)
    part[pos] = make_int2(row[p] | ((c & 255) << 17), // row < 2^17
                          __float_as_int(w[p]));
  }
}

// Fine build: one block per bucket (256 nodes). LDS hist + scan -> row_ptr and
// exact CSR slots; also accumulates deg (raw weight sum) -> dinv, saving a
// separate csr re-read pass.
__global__ __launch_bounds__(256) void build_fine(const int* __restrict__ start,
                                                  const int2* __restrict__ part,
                                                  int* __restrict__ row_ptr,
                                                  int2* __restrict__ csr,
                                                  float* __restrict__ dinv,
                                                  int N) {
  __shared__ int hist[256];
  __shared__ int sc[256];
  __shared__ int cur[256];
  __shared__ float deg[256];
  int b = blockIdx.x;
  int ebeg = start[b], eend = start[b + 1];
  hist[threadIdx.x] = 0;
  deg[threadIdx.x] = 0.f;
  __syncthreads();
  for (int p = ebeg + threadIdx.x; p < eend; p += 256) {
    int2 e = part[p];
    int dl = (e.x >> 17) & 255;
    atomicAdd(&hist[dl], 1);
    lds_fadd(&deg[dl], __int_as_float(e.y));
  }
  ds_drain();          // asm ds_add_f32 invisible to compiler waitcnt tracking
  __syncthreads();
  int v = hist[threadIdx.x];
  sc[threadIdx.x] = v;
  __syncthreads();
  for (int off = 1; off < 256; off <<= 1) {
    int t = (threadIdx.x >= off) ? sc[threadIdx.x - off] : 0;
    __syncthreads();
    sc[threadIdx.x] += t;
    __syncthreads();
  }
  int ex = sc[threadIdx.x] - v;   // exclusive
  int node = b * 256 + threadIdx.x;
  if (node < N) {
    row_ptr[node] = ebeg + ex;
    dinv[node] = 1.0f / sqrtf(1.0f + deg[threadIdx.x]);
  }
  cur[threadIdx.x] = ebeg + ex;
  __syncthreads();
  for (int p = ebeg + threadIdx.x; p < eend; p += 256) {
    int2 r = part[p];
    int pos = atomicAdd(&cur[(r.x >> 17) & 255], 1);       // LDS atomic (int)
    csr[pos] = make_int2(r.x & 0x1FFFF, r.y);
  }
}

// Transpose + bf16-split both weight matrices in ONE launch:
//   i < 16384: W1 (128x128)     -> w1t_hi/lo[n][k]
//   else:      [Wmu|Wls] concat -> wct_hi/lo[n][k], + bias concat.
__global__ __launch_bounds__(256) void prep_weights(
    const float* __restrict__ W1,
    const float* __restrict__ Wmu, const float* __restrict__ Wls,
    const float* __restrict__ bmu, const float* __restrict__ bls,
    unsigned short* __restrict__ w1t_hi, unsigned short* __restrict__ w1t_lo,
    unsigned short* __restrict__ wct_hi, unsigned short* __restrict__ wct_lo,
    float* __restrict__ bcat) {
  int i = blockIdx.x * 256 + threadIdx.x;   // 0..32767
  if (i < 16384) {
    int n = i & 127, k = i >> 7;
    float f = W1[(size_t)k * 128 + n];
    unsigned short h = f2bf_rne(f);
    unsigned short l = f2bf_rne(f - bf2f(h));
    w1t_hi[(size_t)n * 128 + k] = h;
    w1t_lo[(size_t)n * 128 + k] = l;
  } else {
    int j = i - 16384;
    int n = j & 127, k = j >> 7;
    float f = (n < 64) ? Wmu[(size_t)k * 64 + n] : Wls[(size_t)k * 64 + (n - 64)];
    unsigned short h = f2bf_rne(f);
    unsigned short l = f2bf_rne(f - bf2f(h));
    wct_hi[(size_t)n * 128 + k] = h;
    wct_lo[(size_t)n * 128 + k] = l;
    if (j < 128) bcat[j] = (j < 64) ? bmu[j] : bls[j - 64];
  }
}

// C[M,128] = (A[M,128] @ W[128,128]) * rowscale[row] + bias, via split-bf16 MFMA.
// A path: either fp32 (split in-kernel) or PRESPLIT bf16 planes AHi/ALo
// (pure-copy staging, no VALU split). WtHi/WtLo are bf16, TRANSPOSED [n][k].
// Block: 256 thr = 4 waves, C-tile 128x128, wave computes 64x64 (4x4 of 16x16).
// LDS XOR-swizzle: slot ^ (row&7).
// Output: fp32 split (C0 cols<split, C1 rest) and/or bf16 mirror Cbf (stride 128).
__global__ __launch_bounds__(256) void gemm_mfma(
    const float* __restrict__ A,
    const unsigned short* __restrict__ AHi, const unsigned short* __restrict__ ALo,
    const unsigned short* __restrict__ WtHi, const unsigned short* __restrict__ WtLo,
    const float* __restrict__ bias, const float* __restrict__ rowscale,
    float* __restrict__ C0, float* __restrict__ C1,
    unsigned short* __restrict__ Cbf, int split, int M) {
  __shared__ uint4 sAhi[1024];   // [row 0..127][slot 0..7] 16B slots, swizzled
  __shared__ uint4 sAlo[1024];
  __shared__ uint4 sWhi[1024];   // [col 0..127][slot 0..7]
  __shared__ uint4 sWlo[1024];

  int tid = threadIdx.x;
  int lane = tid & 63, wid = tid >> 6;
  int wave_r = (wid >> 1) * 64, wave_c = (wid & 1) * 64;
  int lrow = lane & 15, lkb = lane >> 4;   // lkb = k-chunk 0..3
  int rowBase = blockIdx.x * 128;

  f32x4 acc[4][4];
#pragma unroll
  for (int mr = 0; mr < 4; ++mr)
#pragma unroll
    for (int nc = 0; nc < 4; ++nc) acc[mr][nc] = (f32x4){0.f, 0.f, 0.f, 0.f};

  const uint4* WtHi4 = (const uint4*)WtHi;   // row = 16 uint4 (128 bf16)
  const uint4* WtLo4 = (const uint4*)WtLo;
  const uint4* AHi4 = (const uint4*)AHi;
  const uint4* ALo4 = (const uint4*)ALo;

  for (int kt = 0; kt < 128; kt += 64) {
    __syncthreads();
    // stage W tile: 128 cols x 64 k (bf16, already split) -> swizzled LDS
#pragma unroll
    for (int j = 0; j < 4; ++j) {
      int g = tid + 256 * j;            // 0..1023
      int c = g >> 3, k8 = g & 7;
      int slot = k8 ^ (c & 7);
      sWhi[c * 8 + slot] = WtHi4[c * 16 + (kt >> 3) + k8];
      sWlo[c * 8 + slot] = WtLo4[c * 16 + (kt >> 3) + k8];
    }
    // stage A tile: 128 rows x 64 k -> swizzled LDS
    if (AHi) {
      // presplit path: pure copy
#pragma unroll
      for (int j = 0; j < 4; ++j) {
        int g = tid + 256 * j;
        int r = g >> 3, k8 = g & 7;
        int grow = rowBase + r;
        uint4 vh = make_uint4(0u, 0u, 0u, 0u);
        uint4 vl = vh;
        if (grow < M) {
          vh = AHi4[(size_t)grow * 16 + (kt >> 3) + k8];
          vl = ALo4[(size_t)grow * 16 + (kt >> 3) + k8];
        }
        int slot = k8 ^ (r & 7);
        sAhi[r * 8 + slot] = vh;
        sAlo[r * 8 + slot] = vl;
      }
    } else {
      // fp32 path: split hi/lo in-kernel
#pragma unroll
      for (int j = 0; j < 4; ++j) {
        int g = tid + 256 * j;          // 0..1023
        int r = g >> 3, k8 = g & 7;
        int grow = rowBase + r;
        float4 v0 = make_float4(0.f, 0.f, 0.f, 0.f);
        float4 v1 = v0;
        if (grow < M) {
          const float4* Ar = (const float4*)(A + (size_t)grow * 128 + kt);
          v0 = Ar[k8 * 2];
          v1 = Ar[k8 * 2 + 1];
        }
        float f[8] = {v0.x, v0.y, v0.z, v0.w, v1.x, v1.y, v1.z, v1.w};
        unsigned short h[8], l[8];
#pragma unroll
        for (int q = 0; q < 8; ++q) {
          h[q] = f2bf_rne(f[q]);
          l[q] = f2bf_rne(f[q] - bf2f(h[q]));
        }
        int slot = k8 ^ (r & 7);
        sAhi[r * 8 + slot] = make_uint4(pack2(h[0], h[1]), pack2(h[2], h[3]),
                                        pack2(h[4], h[5]), pack2(h[6], h[7]));
        sAlo[r * 8 + slot] = make_uint4(pack2(l[0], l[1]), pack2(l[2], l[3]),
                                        pack2(l[4], l[5]), pack2(l[6], l[7]));
      }
    }
    __syncthreads();
    // compute: 2 MFMA k-steps (K=32 each) per LDS tile
#pragma unroll
    for (int ks = 0; ks < 2; ++ks) {
      bf16x8 ah[4], al[4], bh[4], bl[4];
#pragma unroll
      for (int mr = 0; mr < 4; ++mr) {
        int r = wave_r + mr * 16 + lrow;
        int slot = (ks * 4 + lkb) ^ (r & 7);
        ah[mr] = *(const bf16x8*)&sAhi[r * 8 + slot];
        al[mr] = *(const bf16x8*)&sAlo[r * 8 + slot];
      }
#pragma unroll
      for (int nc = 0; nc < 4; ++nc) {
        int c = wave_c + nc * 16 + lrow;
        int slot = (ks * 4 + lkb) ^ (c & 7);
        bh[nc] = *(const bf16x8*)&sWhi[c * 8 + slot];
        bl[nc] = *(const bf16x8*)&sWlo[c * 8 + slot];
      }
#pragma unroll
      for (int mr = 0; mr < 4; ++mr)
#pragma unroll
        for (int nc = 0; nc < 4; ++nc) {
          acc[mr][nc] = __builtin_amdgcn_mfma_f32_16x16x32_bf16(
              ah[mr], bh[nc], acc[mr][nc], 0, 0, 0);
          acc[mr][nc] = __builtin_amdgcn_mfma_f32_16x16x32_bf16(
              al[mr], bh[nc], acc[mr][nc], 0, 0, 0);
          acc[mr][nc] = __builtin_amdgcn_mfma_f32_16x16x32_bf16(
              ah[mr], bl[nc], acc[mr][nc], 0, 0, 0);
        }
    }
  }

  // epilogue: D[row=(lane>>4)*4+reg][col=lane&15] per 16x16 tile
#pragma unroll
  for (int mr = 0; mr < 4; ++mr) {
    int Rb = rowBase + wave_r + mr * 16 + lkb * 4;
    float sc[4];
#pragma unroll
    for (int reg = 0; reg < 4; ++reg)
      sc[reg] = (rowscale && (Rb + reg) < M) ? rowscale[Rb + reg] : 1.0f;
#pragma unroll
    for (int nc = 0; nc < 4; ++nc) {
      int c = wave_c + nc * 16 + lrow;
      float bb = bias ? bias[c] : 0.f;
      f32x4 v = acc[mr][nc];
#pragma unroll
      for (int reg = 0; reg < 4; ++reg) {
        int R = Rb + reg;
        if (R >= M) continue;
        float val = v[reg] * sc[reg] + bb;
        if (Cbf) Cbf[(size_t)R * 128 + c] = f2bf_rne(val);
        if (C0) {
          if (c < split) C0[(size_t)R * split + c] = val;
          else           C1[(size_t)R * split + (c - split)] = val;
        }
      }
    }
  }
}

// 256 threads = 8 nodes x 32 lanes; each lane owns 4 channels (ushort4 = 8B bf16).
// Batch-4 edges in flight (proven optimum: 24 VGPR, ~70% occupancy).
// Output: bf16 mirror (hout_bf) and/or PRESPLIT hi/lo bf16 planes (hout_hi/lo,
// split computed in-epilogue, hidden under fabric stalls).
__global__ __launch_bounds__(256) void aggregate(
    const ushort4* __restrict__ hin, const int* __restrict__ row_ptr,
    const int2* __restrict__ csr, const float* __restrict__ dinv,
    const float4* __restrict__ bias4, ushort4* __restrict__ hout_bf,
    ushort4* __restrict__ hout_hi, ushort4* __restrict__ hout_lo,
    int n, int do_relu, int scale_out) {
  int node = blockIdx.x * 8 + (threadIdx.x >> 5);
  if (node >= n) return;
  int t = threadIdx.x & 31;
  int beg = row_ptr[node], end = row_ptr[node + 1];
  ushort4 hs = hin[(size_t)node * 32 + t];   // self-loop (prescaled row)
  float4 acc = make_float4(bf2f(hs.x), bf2f(hs.y), bf2f(hs.z), bf2f(hs.w));
  int p = beg;
  for (; p + 4 <= end; p += 4) {
    int2 e0 = csr[p + 0];
    int2 e1 = csr[p + 1];
    int2 e2 = csr[p + 2];
    int2 e3 = csr[p + 3];
    ushort4 h0 = hin[(size_t)e0.x * 32 + t];
    ushort4 h1 = hin[(size_t)e1.x * 32 + t];
    ushort4 h2 = hin[(size_t)e2.x * 32 + t];
    ushort4 h3 = hin[(size_t)e3.x * 32 + t];
    float w0 = __int_as_float(e0.y), w1 = __int_as_float(e1.y);
    float w2 = __int_as_float(e2.y), w3 = __int_as_float(e3.y);
    acc.x = fmaf(w0, bf2f(h0.x), acc.x); acc.y = fmaf(w0, bf2f(h0.y), acc.y);
    acc.z = fmaf(w0, bf2f(h0.z), acc.z); acc.w = fmaf(w0, bf2f(h0.w), acc.w);
    acc.x = fmaf(w1, bf2f(h1.x), acc.x); acc.y = fmaf(w1, bf2f(h1.y), acc.y);
    acc.z = fmaf(w1, bf2f(h1.z), acc.z); acc.w = fmaf(w1, bf2f(h1.w), acc.w);
    acc.x = fmaf(w2, bf2f(h2.x), acc.x); acc.y = fmaf(w2, bf2f(h2.y), acc.y);
    acc.z = fmaf(w2, bf2f(h2.z), acc.z); acc.w = fmaf(w2, bf2f(h2.w), acc.w);
    acc.x = fmaf(w3, bf2f(h3.x), acc.x); acc.y = fmaf(w3, bf2f(h3.y), acc.y);
    acc.z = fmaf(w3, bf2f(h3.z), acc.z); acc.w = fmaf(w3, bf2f(h3.w), acc.w);
  }
  for (; p < end; ++p) {
    int2 e = csr[p];
    ushort4 hv = hin[(size_t)e.x * 32 + t];
    float wv = __int_as_float(e.y);
    acc.x = fmaf(wv, bf2f(hv.x), acc.x); acc.y = fmaf(wv, bf2f(hv.y), acc.y);
    acc.z = fmaf(wv, bf2f(hv.z), acc.z); acc.w = fmaf(wv, bf2f(hv.w), acc.w);
  }
  float dc = dinv[node];
  float4 val = make_float4(dc * acc.x, dc * acc.y, dc * acc.z, dc * acc.w);
  if (bias4) {
    float4 b = bias4[t];
    val.x += b.x; val.y += b.y; val.z += b.z; val.w += b.w;
  }
  if (do_relu) {
    val.x = fmaxf(val.x, 0.f); val.y = fmaxf(val.y, 0.f);
    val.z = fmaxf(val.z, 0.f); val.w = fmaxf(val.w, 0.f);
  }
  if (scale_out) {
    val.x *= dc; val.y *= dc; val.z *= dc; val.w *= dc;
  }
  size_t o = (size_t)node * 32 + t;
  if (hout_bf) {
    ushort4 ov;
    ov.x = f2bf_rne(val.x); ov.y = f2bf_rne(val.y);
    ov.z = f2bf_rne(val.z); ov.w = f2bf_rne(val.w);
    hout_bf[o] = ov;
  }
  if (hout_hi) {
    ushort4 hv, lv;
    hv.x = f2bf_rne(val.x); lv.x = f2bf_rne(val.x - bf2f(hv.x));
    hv.y = f2bf_rne(val.y); lv.y = f2bf_rne(val.y - bf2f(hv.y));
    hv.z = f2bf_rne(val.z); lv.z = f2bf_rne(val.z - bf2f(hv.z));
    hv.w = f2bf_rne(val.w); lv.w = f2bf_rne(val.w - bf2f(hv.w));
    hout_hi[o] = hv;
    hout_lo[o] = lv;
  }
}

extern "C" void kernel_launch(void* const* d_in, const int* in_sizes, int n_in,
                              void* d_out, int out_size, void* d_ws, size_t ws_size,
                              hipStream_t stream) {
  const float* x   = (const float*)d_in[0];
  const int*   ei  = (const int*)d_in[1];
  const float* ea  = (const float*)d_in[2];
  const float* W1  = (const float*)d_in[3];
  const float* b1  = (const float*)d_in[4];
  const float* Wmu = (const float*)d_in[5];
  const float* bmu = (const float*)d_in[6];
  const float* Wls = (const float*)d_in[7];
  const float* bls = (const float*)d_in[8];
  const int N = in_sizes[0] / 128;
  const int E = in_sizes[2];
  const int* row = ei;
  const int* col = ei + E;

  char* p = (char*)d_ws;
  auto alloc = [&](size_t bytes) -> void* {
    void* r = (void*)p;
    p += (bytes + 255) & ~(size_t)255;
    return r;
  };
  float* dinv    = (float*)alloc((size_t)N * 4);
  int*   row_ptr = (int*)alloc((size_t)(N + 1) * 4);
  int*   start   = (int*)alloc(520 * 4);            // nbuck+1 (<=392)
  unsigned short* w1t_hi = (unsigned short*)alloc(128 * 128 * 2);
  unsigned short* w1t_lo = (unsigned short*)alloc(128 * 128 * 2);
  unsigned short* wct_hi = (unsigned short*)alloc(128 * 128 * 2);
  unsigned short* wct_lo = (unsigned short*)alloc(128 * 128 * 2);
  float* bcat    = (float*)alloc(128 * 4);
  int2*  csr     = (int2*)alloc((size_t)E * 8);
  unsigned short* bufAhi = (unsigned short*)alloc((size_t)N * 128 * 2); // agg2 hi
  unsigned short* bufAlo = (unsigned short*)alloc((size_t)N * 128 * 2); // agg2 lo
  unsigned short* bufB = (unsigned short*)alloc((size_t)N * 128 * 2);  // hs1 bf16
  unsigned short* bufC = (unsigned short*)alloc((size_t)N * 128 * 2);  // out1 bf16

  const int nbuck = (N + 255) >> 8;               // 391 coarse buckets (256 nodes)
  const int epb   = (E + NBLK - 1) / NBLK;        // edges per partition block

  // Aliased scratch (dead before its alias target is first written):
  //  - part (E int2 = 12.8MB) -> bufAhi+bufAlo (first written by agg2, later)
  //  - G / tot                -> bufB (first written by gemm1, after build)
  int2* part = (int2*)bufAhi;
  int*  G    = (int*)bufB;                        // nbuck*NBLK ints = 0.8MB
  int*  tot  = (int*)((char*)bufB + (size_t)nbuck * NBLK * 4);

  float* out_mu = (float*)d_out;
  float* out_ls = out_mu + (size_t)N * 64;

  prep_weights<<<128, 256, 0, stream>>>(W1, Wmu, Wls, bmu, bls,
                                        w1t_hi, w1t_lo, wct_hi, wct_lo, bcat);

  hist_coarse<<<NBLK, 256, 0, stream>>>(col, G, E, nbuck, epb);
  scan_bucket<<<nbuck, NBLK, 0, stream>>>(G, tot);
  scan_start<<<1, 512, 0, stream>>>(tot, start, row_ptr, nbuck, N, E);
  partition_edges<<<NBLK, 256, 0, stream>>>(row, col, ea, G, start, part,
                                            E, nbuck, epb);
  build_fine<<<nbuck, 256, 0, stream>>>(start, part, row_ptr, csr, dinv, N);

  int gblocks = (N + 127) / 128;
  int ablocks = (N + 7) / 8;
  // hs1 = (x @ W1) * dinv[row]  -> bf16 only
  gemm_mfma<<<gblocks, 256, 0, stream>>>(x, nullptr, nullptr, w1t_hi, w1t_lo,
                                         nullptr, dinv, nullptr, nullptr,
                                         bufB, 128, N);
  // out1 = dinv * relu(dinv[c]*(sum w*hs1[r] + hs1[c]) + b1) -> bf16 only
  aggregate<<<ablocks, 256, 0, stream>>>((const ushort4*)bufB, row_ptr, csr, dinv,
                                         (const float4*)b1, (ushort4*)bufC,
                                         nullptr, nullptr, N, 1, 1);
  // agg2 = dinv[c]*(sum w*out1[r] + out1[c])  == A_norm @ h  -> presplit hi/lo
  aggregate<<<ablocks, 256, 0, stream>>>((const ushort4*)bufC, row_ptr, csr, dinv,
                                         nullptr, nullptr, (ushort4*)bufAhi,
                                         (ushort4*)bufAlo, N, 0, 0);
  // [mu | logstd] = agg2 @ [Wmu | Wls] + [bmu | bls]
  gemm_mfma<<<gblocks, 256, 0, stream>>>(nullptr, bufAhi, bufAlo, wct_hi, wct_lo,
                                         bcat, nullptr, out_mu, out_ls,
                                         nullptr, 64, N);
}